// Round 1
// baseline (150.880 us; speedup 1.0000x reference)
//
#include <hip/hip_runtime.h>
#include <hip/hip_bf16.h>
#include <stdint.h>

typedef __bf16 bf16;
typedef __attribute__((ext_vector_type(8))) __bf16 bf16x8;
typedef __attribute__((ext_vector_type(4))) float f32x4;
typedef __attribute__((ext_vector_type(4))) unsigned int u32x4;

#define NH   16
#define SEQ  2048
#define DH   64
#define SCALE 0.125f
#define NEGINF (-1e30f)

// XOR swizzle: row-major [64 rows][128 bytes] bf16 tile; breaks the 16-way
// bank conflict of stride-128B row access (guide §6 G4). Bijective within
// each 8-row stripe; preserves 16B alignment of 16B-aligned chunks.
__device__ __forceinline__ unsigned swz(int row, int bytecol) {
  return (unsigned)(row * 128 + (bytecol ^ ((row & 7) << 4)));
}

// --- mask dtype sniffer ------------------------------------------------
// Bool mask may arrive as 1-byte (numpy bool) or int32 (harness "integer").
// Rows are constant over 64-wide tiles, so in byte form every nonzero
// aligned dword is exactly 0x01010101; in int32 form dwords are 0 or 1.
// Scan 16 spread 4KB chunks (all within the minimal 64MB size).
__global__ void __launch_bounds__(256) mask_detect_kernel(
    const unsigned* __restrict__ m, int* __restrict__ flag) {
  __shared__ int sawByte;
  if (threadIdx.x == 0) sawByte = 0;
  __syncthreads();
  int local = 0;
  for (int c = 0; c < 16; ++c) {
    const unsigned* base = m + (size_t)c * 1048576u;   // 4MB stride (dwords)
    for (int i = threadIdx.x; i < 1024; i += 256) {
      if (base[i] == 0x01010101u) local = 1;
    }
  }
  if (local) atomicOr(&sawByte, 1);
  __syncthreads();
  if (threadIdx.x == 0) flag[0] = sawByte;   // 1 = byte mask, 0 = dword mask
}

// --- main attention kernel --------------------------------------------
// One block per (head, 64-row q-tile). 4 waves; wave w owns q rows
// [16w, 16w+16). Iterate 32 k-tiles of 64 with online softmax.
__global__ void __launch_bounds__(256) sparse_attn_kernel(
    const float* __restrict__ qg, const float* __restrict__ kg,
    const float* __restrict__ vg, const void* __restrict__ maskg,
    float* __restrict__ outg, const int* __restrict__ flagp)
{
  const int bid  = blockIdx.x;
  const int h    = bid >> 5;           // 16 heads
  const int qb   = (bid & 31) << 6;    // q-tile base row
  const int tid  = threadIdx.x;
  const int lane = tid & 63;
  const int w    = tid >> 6;           // wave id 0..3
  const int arow = lane & 15;          // A-frag row / B-frag col
  const int kgrp = lane >> 4;          // k-dim group 0..3
  const int byteMode = flagp[0];

  __shared__ __attribute__((aligned(16))) bf16 Klds[64 * 64];  // [krow][d], swizzled
  __shared__ __attribute__((aligned(16))) bf16 Vlds[64 * 64];  // [d][krow], swizzled (V^T)
  __shared__ __attribute__((aligned(16))) bf16 Plds[64 * 64];  // [qrow][k], swizzled
  __shared__ __attribute__((aligned(16))) unsigned char Mlds[64 * 64];

  // ---- Q fragments: lane holds Q[qb+16w+arow][ks*32+kgrp*8 .. +7] ----
  bf16x8 qa[2];
  {
    const float* qrow = qg + ((size_t)(h * SEQ) + qb + 16 * w + arow) * DH;
    #pragma unroll
    for (int ks = 0; ks < 2; ++ks) {
      const int dbase = ks * 32 + kgrp * 8;
      f32x4 x0 = *(const f32x4*)(qrow + dbase);
      f32x4 x1 = *(const f32x4*)(qrow + dbase + 4);
      bf16x8 a;
      #pragma unroll
      for (int j = 0; j < 4; ++j) { a[j] = (bf16)x0[j]; a[4 + j] = (bf16)x1[j]; }
      qa[ks] = a;
    }
  }

  f32x4 oacc[4];
  #pragma unroll
  for (int nd = 0; nd < 4; ++nd) oacc[nd] = (f32x4){0.f, 0.f, 0.f, 0.f};
  float mrow[4], lrow[4];
  #pragma unroll
  for (int r = 0; r < 4; ++r) { mrow[r] = NEGINF; lrow[r] = 0.f; }

  const int r_st = tid & 63;   // staging row (qrow for mask, krow for K/V)
  const int cgrp = tid >> 6;   // staging 16-element column group

  for (int kt = 0; kt < 32; ++kt) {
    const int kb = kt << 6;
    __syncthreads();   // prev-iter LDS reads complete before restaging

    // ---- stage mask tile as bytes; compute any/all -------------------
    unsigned mw0, mw1, mw2, mw3;
    {
      const size_t moff = ((size_t)(h * SEQ) + qb + r_st) * SEQ + kb + cgrp * 16;
      if (byteMode) {
        u32x4 t = *(const u32x4*)((const unsigned char*)maskg + moff);
        mw0 = t.x; mw1 = t.y; mw2 = t.z; mw3 = t.w;
      } else {
        const int* mp = (const int*)maskg + moff;
        u32x4 t0 = ((const u32x4*)mp)[0];
        u32x4 t1 = ((const u32x4*)mp)[1];
        u32x4 t2 = ((const u32x4*)mp)[2];
        u32x4 t3 = ((const u32x4*)mp)[3];
        mw0 = (t0.x?1u:0u) | ((t0.y?1u:0u)<<8) | ((t0.z?1u:0u)<<16) | ((t0.w?1u:0u)<<24);
        mw1 = (t1.x?1u:0u) | ((t1.y?1u:0u)<<8) | ((t1.z?1u:0u)<<16) | ((t1.w?1u:0u)<<24);
        mw2 = (t2.x?1u:0u) | ((t2.y?1u:0u)<<8) | ((t2.z?1u:0u)<<16) | ((t2.w?1u:0u)<<24);
        mw3 = (t3.x?1u:0u) | ((t3.y?1u:0u)<<8) | ((t3.z?1u:0u)<<16) | ((t3.w?1u:0u)<<24);
      }
    }
    *(u32x4*)&Mlds[r_st * 64 + cgrp * 16] = (u32x4){mw0, mw1, mw2, mw3};
    const unsigned morq = mw0 | mw1 | mw2 | mw3;
    const unsigned mand = mw0 & mw1 & mw2 & mw3;
    const int anyT = __syncthreads_or(morq != 0u);
    const int allT = __syncthreads_and(mand == 0x01010101u);
    if (!anyT) continue;    // fully-masked tile: skip staging + compute

    // ---- stage K (swizzled) and V^T (swizzled) -----------------------
    {
      const float* krow = kg + ((size_t)(h * SEQ) + kb + r_st) * DH + cgrp * 16;
      f32x4 a0 = ((const f32x4*)krow)[0];
      f32x4 a1 = ((const f32x4*)krow)[1];
      f32x4 a2 = ((const f32x4*)krow)[2];
      f32x4 a3 = ((const f32x4*)krow)[3];
      bf16x8 b0, b1;
      #pragma unroll
      for (int j = 0; j < 4; ++j) {
        b0[j] = (bf16)a0[j]; b0[4 + j] = (bf16)a1[j];
        b1[j] = (bf16)a2[j]; b1[4 + j] = (bf16)a3[j];
      }
      *(bf16x8*)((char*)Klds + swz(r_st, cgrp * 32))      = b0;
      *(bf16x8*)((char*)Klds + swz(r_st, cgrp * 32 + 16)) = b1;

      const float* vrow = vg + ((size_t)(h * SEQ) + kb + r_st) * DH + cgrp * 16;
      f32x4 vr[4];
      vr[0] = ((const f32x4*)vrow)[0];
      vr[1] = ((const f32x4*)vrow)[1];
      vr[2] = ((const f32x4*)vrow)[2];
      vr[3] = ((const f32x4*)vrow)[3];
      #pragma unroll
      for (int j = 0; j < 16; ++j) {
        const int d = cgrp * 16 + j;
        *(bf16*)((char*)Vlds + swz(d, 2 * r_st)) = (bf16)vr[j >> 2][j & 3];
      }
    }
    __syncthreads();

    // ---- S = Q K^T (per wave: 16 rows x 64 cols, 4 C-frags) ----------
    f32x4 sfr[4];
    #pragma unroll
    for (int nd = 0; nd < 4; ++nd) sfr[nd] = (f32x4){0.f, 0.f, 0.f, 0.f};
    #pragma unroll
    for (int nd = 0; nd < 4; ++nd) {
      #pragma unroll
      for (int ks = 0; ks < 2; ++ks) {
        bf16x8 b = *(const bf16x8*)((char*)Klds + swz(16 * nd + arow, ks * 64 + kgrp * 16));
        sfr[nd] = __builtin_amdgcn_mfma_f32_16x16x32_bf16(qa[ks], b, sfr[nd], 0, 0, 0);
      }
    }

    // ---- mask, online softmax, P -> LDS (bf16, swizzled) -------------
    // C/D layout: col = 16*nd + (lane&15), row(local16) = (lane>>4)*4 + r.
    #pragma unroll
    for (int r = 0; r < 4; ++r) {
      const int rloc = 16 * w + kgrp * 4 + r;   // block-local q row
      float sv[4];
      #pragma unroll
      for (int nd = 0; nd < 4; ++nd) {
        float x = sfr[nd][r] * SCALE;
        if (!allT && !Mlds[rloc * 64 + 16 * nd + arow]) x = NEGINF;
        sv[nd] = x;
      }
      float tmax = fmaxf(fmaxf(sv[0], sv[1]), fmaxf(sv[2], sv[3]));
      #pragma unroll
      for (int off = 8; off >= 1; off >>= 1)
        tmax = fmaxf(tmax, __shfl_xor(tmax, off));
      const float mn  = fmaxf(mrow[r], tmax);
      const float fac = __expf(mrow[r] - mn);   // 0 if first real tile, 1 if unchanged
      float ps = 0.f;
      bf16 pb[4];
      #pragma unroll
      for (int nd = 0; nd < 4; ++nd) {
        // guard: fully-masked row keeps p = 0 (so l stays 0 -> output 0)
        float p = (sv[nd] > -1e20f) ? __expf(sv[nd] - mn) : 0.f;
        ps += p; pb[nd] = (bf16)p;
      }
      #pragma unroll
      for (int off = 8; off >= 1; off >>= 1)
        ps += __shfl_xor(ps, off);
      lrow[r] = lrow[r] * fac + ps;
      mrow[r] = mn;
      #pragma unroll
      for (int nd = 0; nd < 4; ++nd) {
        oacc[nd][r] *= fac;
        *(bf16*)((char*)Plds + swz(rloc, 2 * (16 * nd + arow))) = pb[nd];
      }
    }

    // ---- O += P V  (wave reads only its OWN P rows: no barrier) ------
    #pragma unroll
    for (int ks = 0; ks < 2; ++ks) {
      bf16x8 ap = *(const bf16x8*)((char*)Plds + swz(16 * w + arow, ks * 64 + kgrp * 16));
      #pragma unroll
      for (int nd = 0; nd < 4; ++nd) {
        bf16x8 bv = *(const bf16x8*)((char*)Vlds + swz(16 * nd + arow, ks * 64 + kgrp * 16));
        oacc[nd] = __builtin_amdgcn_mfma_f32_16x16x32_bf16(ap, bv, oacc[nd], 0, 0, 0);
      }
    }
  }

  // ---- epilogue: out = O / l  (0 if l == 0) --------------------------
  #pragma unroll
  for (int r = 0; r < 4; ++r) {
    const float li  = lrow[r];
    const float inv = (li > 0.f) ? (1.f / li) : 0.f;
    const int grow  = qb + 16 * w + kgrp * 4 + r;
    #pragma unroll
    for (int nd = 0; nd < 4; ++nd) {
      outg[((size_t)(h * SEQ) + grow) * DH + 16 * nd + arow] = oacc[nd][r] * inv;
    }
  }
}

extern "C" void kernel_launch(void* const* d_in, const int* in_sizes, int n_in,
                              void* d_out, int out_size, void* d_ws, size_t ws_size,
                              hipStream_t stream) {
  const float* q = (const float*)d_in[0];
  const float* k = (const float*)d_in[1];
  const float* v = (const float*)d_in[2];
  const void*  m = d_in[3];
  float* out = (float*)d_out;
  int* flag = (int*)d_ws;

  mask_detect_kernel<<<1, 256, 0, stream>>>((const unsigned*)m, flag);
  sparse_attn_kernel<<<NH * (SEQ / 64), 256, 0, stream>>>(q, k, v, m, out, flag);
}

// Round 2
// 140.811 us; speedup vs baseline: 1.0715x; 1.0715x over previous
//
#include <hip/hip_runtime.h>
#include <hip/hip_bf16.h>
#include <stdint.h>

typedef __bf16 bf16;
typedef __attribute__((ext_vector_type(8))) __bf16 bf16x8;
typedef __attribute__((ext_vector_type(4))) float f32x4;
typedef __attribute__((ext_vector_type(4))) unsigned int u32x4;

#define NH   16
#define SEQ  2048
#define DH   64
#define NT   32            // 64-wide tiles per sequence dim
#define SCALE 0.125f
#define NEGINF (-1e30f)

// ws layout
struct TileList { int count; int pad[3]; unsigned char e[32]; int pad2[4]; }; // 64B
#define WS_LISTS 64
#define WS_KIMG  65536
#define IMG_TILE 8192
#define WS_VIMG  (WS_KIMG + (size_t)NH * NT * IMG_TILE)
#define WS_NEED  (WS_VIMG + (size_t)NH * NT * IMG_TILE)

// XOR swizzle for row-major [64][128B] bf16 tiles (G4: kills the 16-way
// conflict of stride-128B column access). Preserves 16B chunk alignment.
__device__ __forceinline__ unsigned swz(int row, int bytecol) {
  return (unsigned)(row * 128 + (bytecol ^ ((row & 7) << 4)));
}

__device__ __forceinline__ void gload_lds16(const void* g, void* l) {
  __builtin_amdgcn_global_load_lds(
      (const __attribute__((address_space(1))) unsigned int*)g,
      (__attribute__((address_space(3))) unsigned int*)l, 16, 0, 0);
}

// --- mask dtype sniffer (byte vs int32 bool) ---------------------------
__global__ void __launch_bounds__(256) mask_detect_kernel(
    const unsigned* __restrict__ m, int* __restrict__ flag) {
  __shared__ int sawByte;
  if (threadIdx.x == 0) sawByte = 0;
  __syncthreads();
  int local = 0;
  for (int c = 0; c < 16; ++c) {
    const unsigned* base = m + (size_t)c * 1048576u;   // 4MB stride
    for (int i = threadIdx.x; i < 1024; i += 256)
      if (base[i] == 0x01010101u) local = 1;
  }
  if (local) atomicOr(&sawByte, 1);
  __syncthreads();
  if (threadIdx.x == 0) flag[0] = sawByte;   // 1 = byte mask, 0 = dword mask
}

// --- pre-pass A: per-(h,qtile) compacted active-ktile list -------------
// Block = (h, qt). Wave w scans ktiles {4t+w}; lane reduction only, one
// barrier per block. Entry byte: kt | (all?0x80:0), ascending kt.
__global__ void __launch_bounds__(256) tile_scan_kernel(
    const void* __restrict__ maskg, const int* __restrict__ flagp,
    TileList* __restrict__ lists) {
  const int bid = blockIdx.x;
  const int h = bid >> 5, qt = bid & 31;
  const int qb = qt * 64;
  const int tid = threadIdx.x, l = tid & 63, w = tid >> 6;
  const int byteMode = flagp[0];
  __shared__ unsigned char flags[32];

  for (int t = 0; t < 8; ++t) {
    const int kt = 4 * t + w;
    unsigned ored = 0u, anded = 0xFFFFFFFFu;
    if (byteMode) {
      const unsigned char* mb = (const unsigned char*)maskg;
      #pragma unroll
      for (int j = 0; j < 4; ++j) {
        const int row = 16 * j + (l >> 2);
        u32x4 v = *(const u32x4*)(mb + ((size_t)(h * SEQ) + qb + row) * SEQ + kt * 64 + (l & 3) * 16);
        ored |= v.x | v.y | v.z | v.w;
        anded &= v.x & v.y & v.z & v.w;
      }
    } else {
      const unsigned* md = (const unsigned*)maskg;
      #pragma unroll
      for (int j = 0; j < 4; ++j) {
        const int row = 16 * j + (l >> 2);
        const unsigned* bp = md + ((size_t)(h * SEQ) + qb + row) * SEQ + kt * 64 + (l & 3) * 16;
        #pragma unroll
        for (int q = 0; q < 4; ++q) {
          u32x4 v = ((const u32x4*)bp)[q];
          ored |= v.x | v.y | v.z | v.w;
          anded &= v.x & v.y & v.z & v.w;
        }
      }
    }
    const unsigned tgt = byteMode ? 0x01010101u : 1u;
    const int any = __any(ored != 0u);
    const int all = __all(anded == tgt);
    if (l == 0) flags[kt] = (unsigned char)((any ? 1 : 0) | (all ? 2 : 0));
  }
  __syncthreads();
  if (tid == 0) {
    TileList* L = lists + bid;          // bid == h*32+qt
    int n = 0;
    for (int kt = 0; kt < 32; ++kt) {
      const unsigned f = flags[kt];
      if (f & 1) L->e[n++] = (unsigned char)(kt | ((f & 2) ? 0x80 : 0));
    }
    for (int i = n; i < 32; ++i) L->e[i] = 0;
    L->count = n;
  }
}

// --- pre-pass B: K and V^T tiles -> bf16 LDS-image layout in ws --------
__global__ void __launch_bounds__(256) convert_kernel(
    const float* __restrict__ kg, const float* __restrict__ vg,
    unsigned char* __restrict__ kimg, unsigned char* __restrict__ vimg) {
  const int bid = blockIdx.x;
  const int h = bid & 15, kt = bid >> 4;
  const int kb = kt * 64;
  const int tid = threadIdx.x, r = tid & 63, cg = tid >> 6;
  __shared__ __attribute__((aligned(16))) unsigned char Ki[IMG_TILE];
  __shared__ __attribute__((aligned(16))) unsigned char Vi[IMG_TILE];

  {
    const float* kr = kg + ((size_t)(h * SEQ) + kb + r) * DH + cg * 16;
    f32x4 a0 = ((const f32x4*)kr)[0], a1 = ((const f32x4*)kr)[1];
    f32x4 a2 = ((const f32x4*)kr)[2], a3 = ((const f32x4*)kr)[3];
    bf16x8 b0, b1;
    #pragma unroll
    for (int j = 0; j < 4; ++j) {
      b0[j] = (bf16)a0[j]; b0[4 + j] = (bf16)a1[j];
      b1[j] = (bf16)a2[j]; b1[4 + j] = (bf16)a3[j];
    }
    *(bf16x8*)(Ki + swz(r, cg * 32))      = b0;
    *(bf16x8*)(Ki + swz(r, cg * 32 + 16)) = b1;

    const float* vr = vg + ((size_t)(h * SEQ) + kb + r) * DH + cg * 16;
    f32x4 v0 = ((const f32x4*)vr)[0], v1 = ((const f32x4*)vr)[1];
    f32x4 v2 = ((const f32x4*)vr)[2], v3 = ((const f32x4*)vr)[3];
    f32x4 vv[4] = {v0, v1, v2, v3};
    #pragma unroll
    for (int j = 0; j < 16; ++j) {
      const int d = cg * 16 + j;
      *(bf16*)(Vi + swz(d, 2 * r)) = (bf16)vv[j >> 2][j & 3];
    }
  }
  __syncthreads();
  const size_t off = (size_t)(h * NT + kt) * IMG_TILE;
  u32x4* ko = (u32x4*)(kimg + off);
  u32x4* vo = (u32x4*)(vimg + off);
  ko[tid * 2]     = ((const u32x4*)Ki)[tid * 2];
  ko[tid * 2 + 1] = ((const u32x4*)Ki)[tid * 2 + 1];
  vo[tid * 2]     = ((const u32x4*)Vi)[tid * 2];
  vo[tid * 2 + 1] = ((const u32x4*)Vi)[tid * 2 + 1];
}

// --- main attention kernel ---------------------------------------------
// Block = (h = bid&15 -> XCD-local heads, qt = bid>>4). 4 waves x 16 q-rows.
// Iterates only active k-tiles from the list; double-buffered LDS; one
// barrier per tile; tile i+1 staged (DMA or reg-prefetch) under compute i.
template<bool IMG>
__global__ void __launch_bounds__(256) sparse_attn_kernel(
    const float* __restrict__ qg, const float* __restrict__ kg,
    const float* __restrict__ vg, const void* __restrict__ maskg,
    float* __restrict__ outg, const int* __restrict__ flagp,
    const TileList* __restrict__ lists,
    const unsigned char* __restrict__ kimg, const unsigned char* __restrict__ vimg)
{
  const int bid  = blockIdx.x;
  const int h    = bid & 15;
  const int qt   = bid >> 4;
  const int qb   = qt << 6;
  const int tid  = threadIdx.x;
  const int lane = tid & 63;
  const int w    = tid >> 6;
  const int arow = lane & 15;
  const int kgrp = lane >> 4;
  const int cg   = w;                 // staging column group
  const int byteMode = flagp[0];

  __shared__ __attribute__((aligned(16))) bf16 Kl[2][4096];
  __shared__ __attribute__((aligned(16))) bf16 Vl[2][4096];
  __shared__ __attribute__((aligned(16))) bf16 Pl[4096];

  // ---- Q fragments ----
  bf16x8 qa[2];
  {
    const float* qrow = qg + ((size_t)(h * SEQ) + qb + 16 * w + arow) * DH;
    #pragma unroll
    for (int ks = 0; ks < 2; ++ks) {
      const int dbase = ks * 32 + kgrp * 8;
      f32x4 x0 = *(const f32x4*)(qrow + dbase);
      f32x4 x1 = *(const f32x4*)(qrow + dbase + 4);
      bf16x8 a;
      #pragma unroll
      for (int j = 0; j < 4; ++j) { a[j] = (bf16)x0[j]; a[4 + j] = (bf16)x1[j]; }
      qa[ks] = a;
    }
  }

  f32x4 oacc[4];
  #pragma unroll
  for (int nd = 0; nd < 4; ++nd) oacc[nd] = (f32x4){0.f, 0.f, 0.f, 0.f};
  float mrow[4], lrow[4];
  #pragma unroll
  for (int r = 0; r < 4; ++r) { mrow[r] = NEGINF; lrow[r] = 0.f; }

  const TileList* L = lists + (h * NT + qt);
  const int cnt = L->count;

  // ---- prologue: stage tile 0 into buf0 ----
  if (cnt > 0) {
    const int kt0 = L->e[0] & 63;
    if constexpr (IMG) {
      const size_t toff = (size_t)(h * NT + kt0) * IMG_TILE;
      const unsigned char* ks = kimg + toff + w * 1024 + lane * 16;
      const unsigned char* vs = vimg + toff + w * 1024 + lane * 16;
      char* kl = (char*)&Kl[0][0] + w * 1024;
      char* vl = (char*)&Vl[0][0] + w * 1024;
      gload_lds16(ks, kl); gload_lds16(ks + 4096, kl + 4096);
      gload_lds16(vs, vl); gload_lds16(vs + 4096, vl + 4096);
    } else {
      const float* kr = kg + ((size_t)(h * SEQ) + kt0 * 64 + lane) * DH + cg * 16;
      f32x4 a0 = ((const f32x4*)kr)[0], a1 = ((const f32x4*)kr)[1];
      f32x4 a2 = ((const f32x4*)kr)[2], a3 = ((const f32x4*)kr)[3];
      bf16x8 b0, b1;
      #pragma unroll
      for (int j = 0; j < 4; ++j) {
        b0[j] = (bf16)a0[j]; b0[4 + j] = (bf16)a1[j];
        b1[j] = (bf16)a2[j]; b1[4 + j] = (bf16)a3[j];
      }
      *(bf16x8*)((char*)&Kl[0][0] + swz(lane, cg * 32))      = b0;
      *(bf16x8*)((char*)&Kl[0][0] + swz(lane, cg * 32 + 16)) = b1;
      const float* vr = vg + ((size_t)(h * SEQ) + kt0 * 64 + lane) * DH + cg * 16;
      f32x4 vv[4];
      vv[0] = ((const f32x4*)vr)[0]; vv[1] = ((const f32x4*)vr)[1];
      vv[2] = ((const f32x4*)vr)[2]; vv[3] = ((const f32x4*)vr)[3];
      #pragma unroll
      for (int j = 0; j < 16; ++j) {
        const int d = cg * 16 + j;
        *(bf16*)((char*)&Vl[0][0] + swz(d, 2 * lane)) = (bf16)vv[j >> 2][j & 3];
      }
    }
  }
  __syncthreads();

  // ---- main loop over active tiles ----
  for (int idx = 0; idx < cnt; ++idx) {
    const int cur = idx & 1;
    const unsigned ecur = L->e[idx];
    const int kb = (int)(ecur & 63) << 6;
    const int allT = (ecur & 0x80) != 0;

    // stage next tile (DMA now / regs now + LDS write after compute)
    f32x4 kreg[4], vreg[4];
    const int haveNext = (idx + 1 < cnt);
    if (haveNext) {
      const int ktn = L->e[idx + 1] & 63;
      if constexpr (IMG) {
        const size_t toff = (size_t)(h * NT + ktn) * IMG_TILE;
        const unsigned char* ks = kimg + toff + w * 1024 + lane * 16;
        const unsigned char* vs = vimg + toff + w * 1024 + lane * 16;
        char* kl = (char*)&Kl[cur ^ 1][0] + w * 1024;
        char* vl = (char*)&Vl[cur ^ 1][0] + w * 1024;
        gload_lds16(ks, kl); gload_lds16(ks + 4096, kl + 4096);
        gload_lds16(vs, vl); gload_lds16(vs + 4096, vl + 4096);
      } else {
        const float* kr = kg + ((size_t)(h * SEQ) + ktn * 64 + lane) * DH + cg * 16;
        kreg[0] = ((const f32x4*)kr)[0]; kreg[1] = ((const f32x4*)kr)[1];
        kreg[2] = ((const f32x4*)kr)[2]; kreg[3] = ((const f32x4*)kr)[3];
        const float* vr = vg + ((size_t)(h * SEQ) + ktn * 64 + lane) * DH + cg * 16;
        vreg[0] = ((const f32x4*)vr)[0]; vreg[1] = ((const f32x4*)vr)[1];
        vreg[2] = ((const f32x4*)vr)[2]; vreg[3] = ((const f32x4*)vr)[3];
      }
    }

    // ---- S = Q K^T ----
    const char* kbuf = (const char*)&Kl[cur][0];
    f32x4 sfr[4];
    #pragma unroll
    for (int nd = 0; nd < 4; ++nd) sfr[nd] = (f32x4){0.f, 0.f, 0.f, 0.f};
    #pragma unroll
    for (int nd = 0; nd < 4; ++nd) {
      #pragma unroll
      for (int ks = 0; ks < 2; ++ks) {
        bf16x8 b = *(const bf16x8*)(kbuf + swz(16 * nd + arow, ks * 64 + kgrp * 16));
        sfr[nd] = __builtin_amdgcn_mfma_f32_16x16x32_bf16(qa[ks], b, sfr[nd], 0, 0, 0);
      }
    }

    // ---- mask (partial tiles only, direct from global), online softmax ----
    #pragma unroll
    for (int r = 0; r < 4; ++r) {
      const int rloc = 16 * w + kgrp * 4 + r;
      float sv[4];
      #pragma unroll
      for (int nd = 0; nd < 4; ++nd) sv[nd] = sfr[nd][r] * SCALE;
      if (!allT) {
        const size_t rowoff = ((size_t)(h * SEQ) + qb + rloc) * SEQ + kb;
        #pragma unroll
        for (int nd = 0; nd < 4; ++nd) {
          const size_t off = rowoff + 16 * nd + arow;
          const bool mv = byteMode ? (((const unsigned char*)maskg)[off] != 0)
                                   : (((const unsigned*)maskg)[off] != 0u);
          if (!mv) sv[nd] = NEGINF;
        }
      }
      float tmax = fmaxf(fmaxf(sv[0], sv[1]), fmaxf(sv[2], sv[3]));
      #pragma unroll
      for (int off = 8; off >= 1; off >>= 1)
        tmax = fmaxf(tmax, __shfl_xor(tmax, off));
      const float mn  = fmaxf(mrow[r], tmax);
      const float fac = __expf(mrow[r] - mn);
      float ps = 0.f;
      bf16 pb[4];
      #pragma unroll
      for (int nd = 0; nd < 4; ++nd) {
        const float p = (sv[nd] > -1e20f) ? __expf(sv[nd] - mn) : 0.f;
        ps += p; pb[nd] = (bf16)p;
      }
      #pragma unroll
      for (int off = 8; off >= 1; off >>= 1)
        ps += __shfl_xor(ps, off);
      lrow[r] = lrow[r] * fac + ps;
      mrow[r] = mn;
      #pragma unroll
      for (int nd = 0; nd < 4; ++nd) {
        oacc[nd][r] *= fac;
        *(bf16*)((char*)Pl + swz(rloc, 2 * (16 * nd + arow))) = pb[nd];
      }
    }

    // ---- O += P V (wave-private P rows: no barrier) ----
    const char* vbuf = (const char*)&Vl[cur][0];
    #pragma unroll
    for (int ks = 0; ks < 2; ++ks) {
      bf16x8 ap = *(const bf16x8*)((char*)Pl + swz(16 * w + arow, ks * 64 + kgrp * 16));
      #pragma unroll
      for (int nd = 0; nd < 4; ++nd) {
        bf16x8 bv = *(const bf16x8*)(vbuf + swz(16 * nd + arow, ks * 64 + kgrp * 16));
        oacc[nd] = __builtin_amdgcn_mfma_f32_16x16x32_bf16(ap, bv, oacc[nd], 0, 0, 0);
      }
    }

    // ---- fallback: write prefetched regs to the other buffer ----
    if constexpr (!IMG) {
      if (haveNext) {
        bf16x8 b0, b1;
        #pragma unroll
        for (int j = 0; j < 4; ++j) {
          b0[j] = (bf16)kreg[0][j]; b0[4 + j] = (bf16)kreg[1][j];
          b1[j] = (bf16)kreg[2][j]; b1[4 + j] = (bf16)kreg[3][j];
        }
        char* kb8 = (char*)&Kl[cur ^ 1][0];
        *(bf16x8*)(kb8 + swz(lane, cg * 32))      = b0;
        *(bf16x8*)(kb8 + swz(lane, cg * 32 + 16)) = b1;
        char* vb8 = (char*)&Vl[cur ^ 1][0];
        #pragma unroll
        for (int j = 0; j < 16; ++j) {
          const int d = cg * 16 + j;
          *(bf16*)(vb8 + swz(d, 2 * lane)) = (bf16)vreg[j >> 2][j & 3];
        }
      }
    }
    __syncthreads();   // drains next-tile DMA; protects buffer reuse
  }

  // ---- epilogue ----
  #pragma unroll
  for (int r = 0; r < 4; ++r) {
    const float li  = lrow[r];
    const float inv = (li > 0.f) ? (1.f / li) : 0.f;
    const int grow  = qb + 16 * w + kgrp * 4 + r;
    #pragma unroll
    for (int nd = 0; nd < 4; ++nd) {
      outg[((size_t)(h * SEQ) + grow) * DH + 16 * nd + arow] = oacc[nd][r] * inv;
    }
  }
}

template __global__ void sparse_attn_kernel<true>(
    const float*, const float*, const float*, const void*, float*,
    const int*, const TileList*, const unsigned char*, const unsigned char*);
template __global__ void sparse_attn_kernel<false>(
    const float*, const float*, const float*, const void*, float*,
    const int*, const TileList*, const unsigned char*, const unsigned char*);

extern "C" void kernel_launch(void* const* d_in, const int* in_sizes, int n_in,
                              void* d_out, int out_size, void* d_ws, size_t ws_size,
                              hipStream_t stream) {
  const float* q = (const float*)d_in[0];
  const float* k = (const float*)d_in[1];
  const float* v = (const float*)d_in[2];
  const void*  m = d_in[3];
  float* out = (float*)d_out;

  unsigned char* ws = (unsigned char*)d_ws;
  int* flag = (int*)ws;
  TileList* lists = (TileList*)(ws + WS_LISTS);
  const bool img = ws_size >= WS_NEED;

  mask_detect_kernel<<<1, 256, 0, stream>>>((const unsigned*)m, flag);
  tile_scan_kernel<<<NH * NT, 256, 0, stream>>>(m, flag, lists);
  if (img) {
    convert_kernel<<<NH * NT, 256, 0, stream>>>(k, v, ws + WS_KIMG, ws + WS_VIMG);
    sparse_attn_kernel<true><<<NH * NT, 256, 0, stream>>>(
        q, k, v, m, out, flag, lists, ws + WS_KIMG, ws + WS_VIMG);
  } else {
    sparse_attn_kernel<false><<<NH * NT, 256, 0, stream>>>(
        q, k, v, m, out, flag, lists, nullptr, nullptr);
  }
}

// Round 3
// 133.084 us; speedup vs baseline: 1.1337x; 1.0581x over previous
//
#include <hip/hip_runtime.h>
#include <hip/hip_bf16.h>
#include <stdint.h>

typedef __bf16 bf16;
typedef __attribute__((ext_vector_type(8))) __bf16 bf16x8;
typedef __attribute__((ext_vector_type(4))) float f32x4;
typedef __attribute__((ext_vector_type(4))) unsigned int u32x4;

#define NH 16
#define SEQ 2048
#define DH 64
#define NT 32
#define SCALE 0.125f
#define NEGINF (-1e30f)

#define IMG_TILE 8192
#define WS_KIMG  65536
#define WS_VIMG  (WS_KIMG + (size_t)NH * NT * IMG_TILE)   // +4 MiB
#define WS_NEED  (WS_VIMG + (size_t)NH * NT * IMG_TILE)

// XOR swizzle for row-major [rows][128 B] bf16 tiles (G4: kills the 16-way
// bank conflict of stride-128B column access). Chunk-granular (16 B).
__device__ __forceinline__ unsigned swz(int row, int bytecol) {
  return (unsigned)(row * 128 + (bytecol ^ ((row & 7) << 4)));
}

__device__ __forceinline__ void gload_lds16(const void* g, void* l) {
  __builtin_amdgcn_global_load_lds(
      (const __attribute__((address_space(1))) unsigned int*)g,
      (__attribute__((address_space(3))) unsigned int*)l, 16, 0, 0);
}

// mask dtype sniff: every block samples 4 KB; byte-bool masks show 0x01010101
// dwords (tile-constant rows), int32-bool masks show dwords == 1.
__device__ __forceinline__ void sniff(const void* maskg, int* flag, int b, int tid) {
  const u32x4* sp = (const u32x4*)((const unsigned char*)maskg + (size_t)b * 131072u);
  u32x4 v = sp[tid];
  int bits = 0;
  #pragma unroll
  for (int j = 0; j < 4; ++j) {
    const unsigned x = v[j];
    if (x == 0x01010101u) bits |= 1;
    else if (x == 1u) bits |= 2;
  }
  const int bb = __any(bits & 1) ? 1 : 0;
  const int db = __any(bits & 2) ? 2 : 0;
  if ((tid & 63) == 0 && (bb | db)) atomicOr(flag, bb | db);
}

// prep: sniff + (optionally) convert K and V^T tiles into bf16 swizzled
// LDS-image layout in ws. Block b -> head h = b&15 (XCD-local), ktile b>>4.
template<bool CONV>
__global__ void __launch_bounds__(256) prep_kernel(
    const float* __restrict__ kg, const float* __restrict__ vg,
    const void* __restrict__ maskg,
    unsigned char* __restrict__ kimg, unsigned char* __restrict__ vimg,
    int* __restrict__ flag)
{
  const int b = blockIdx.x, tid = threadIdx.x;
  sniff(maskg, flag, b, tid);
  if constexpr (!CONV) return;

  const int h = b & 15, kt = b >> 4, kb = kt * 64;
  const int r = tid & 63, cg = tid >> 6;
  __shared__ __attribute__((aligned(16))) unsigned char Ki[IMG_TILE];
  __shared__ __attribute__((aligned(16))) unsigned char Vi[IMG_TILE];

  {
    const float* kr = kg + ((size_t)(h * SEQ) + kb + r) * DH + cg * 16;
    f32x4 a0 = ((const f32x4*)kr)[0], a1 = ((const f32x4*)kr)[1];
    f32x4 a2 = ((const f32x4*)kr)[2], a3 = ((const f32x4*)kr)[3];
    bf16x8 b0, b1;
    #pragma unroll
    for (int j = 0; j < 4; ++j) {
      b0[j] = (bf16)a0[j]; b0[4 + j] = (bf16)a1[j];
      b1[j] = (bf16)a2[j]; b1[4 + j] = (bf16)a3[j];
    }
    *(bf16x8*)(Ki + swz(r, cg * 32))      = b0;
    *(bf16x8*)(Ki + swz(r, cg * 32 + 16)) = b1;

    const float* vr = vg + ((size_t)(h * SEQ) + kb + r) * DH + cg * 16;
    f32x4 v0 = ((const f32x4*)vr)[0], v1 = ((const f32x4*)vr)[1];
    f32x4 v2 = ((const f32x4*)vr)[2], v3 = ((const f32x4*)vr)[3];
    f32x4 vv[4] = {v0, v1, v2, v3};
    #pragma unroll
    for (int j = 0; j < 16; ++j) {
      const int d = cg * 16 + j;
      *(bf16*)(Vi + swz(d, 2 * r)) = (bf16)vv[j >> 2][j & 3];   // V^T [d][2*krow]
    }
  }
  __syncthreads();
  const size_t off = (size_t)(h * NT + kt) * IMG_TILE;
  u32x4* ko = (u32x4*)(kimg + off);
  u32x4* vo = (u32x4*)(vimg + off);
  ko[tid * 2]     = ((const u32x4*)Ki)[tid * 2];
  ko[tid * 2 + 1] = ((const u32x4*)Ki)[tid * 2 + 1];
  vo[tid * 2]     = ((const u32x4*)Vi)[tid * 2];
  vo[tid * 2 + 1] = ((const u32x4*)Vi)[tid * 2 + 1];
}

// attn: block = (h = bid&15, 64-row qtile = bid>>4). 8 waves = ksplit 2 x
// rowwaves 4; split s handles k-rows [32s,32s+32) of every active tile.
// In-block mask scan -> LDS list; double-buffered staging; one barrier/tile;
// final (m,l,O) merge across splits via LDS.
template<bool IMG>
__global__ void __launch_bounds__(512, 4) attn_kernel(
    const float* __restrict__ qg, const float* __restrict__ kg,
    const float* __restrict__ vg, const void* __restrict__ maskg,
    float* __restrict__ outg, const int* __restrict__ flagp,
    const unsigned char* __restrict__ kimg, const unsigned char* __restrict__ vimg)
{
  const int bid = blockIdx.x;
  const int h = bid & 15, qt = bid >> 4, qb = qt << 6;
  const int tid = threadIdx.x, l = tid & 63, w = tid >> 6;
  const int s = w >> 2, rw = w & 3;            // ksplit, row-wave
  const int arow = l & 15, kgrp = l >> 4;
  const int fl = flagp[0];
  const int byteMode = (fl & 1) ? 1 : ((fl & 2) ? 0 : 1);

  __shared__ __attribute__((aligned(16))) bf16 Kb[2][2][2048];  // [s][buf] 32x128B
  __shared__ __attribute__((aligned(16))) bf16 Vb[2][2][4096];  // [s][buf] 64x128B (V^T, half-used)
  __shared__ __attribute__((aligned(16))) bf16 Pb[2][4096];     // [s] 64x128B (half-used)
  __shared__ unsigned char tfl[32];
  __shared__ unsigned char lst[32];
  __shared__ int lcnt;

  // ---- Q fragments (both splits load the same rows) ----
  bf16x8 qa[2];
  {
    const float* qrow = qg + ((size_t)(h * SEQ) + qb + 16 * rw + arow) * DH;
    #pragma unroll
    for (int ks = 0; ks < 2; ++ks) {
      const int dbase = ks * 32 + kgrp * 8;
      f32x4 x0 = *(const f32x4*)(qrow + dbase);
      f32x4 x1 = *(const f32x4*)(qrow + dbase + 4);
      bf16x8 a;
      #pragma unroll
      for (int j = 0; j < 4; ++j) { a[j] = (bf16)x0[j]; a[4 + j] = (bf16)x1[j]; }
      qa[ks] = a;
    }
  }

  // ---- in-block mask scan: dtype-agnostic classification ----
  {
    const int kt = w * 4 + (l >> 4);       // 0..31 (8 waves x 4)
    const int sub = l & 15;
    unsigned ored = 0u, anded = 0xFFFFFFFFu;
    if (byteMode) {
      const unsigned char* mb = (const unsigned char*)maskg;
      #pragma unroll
      for (int i = 0; i < 4; ++i) {
        const unsigned char* p = mb + ((size_t)(h * SEQ) + qb + sub * 4 + i) * SEQ + kt * 64;
        #pragma unroll
        for (int j = 0; j < 4; ++j) {
          u32x4 t = ((const u32x4*)p)[j];
          ored |= t[0] | t[1] | t[2] | t[3];
          anded &= t[0] & t[1] & t[2] & t[3];
        }
      }
    } else {
      const unsigned* md = (const unsigned*)maskg;
      #pragma unroll
      for (int i = 0; i < 4; ++i) {
        const unsigned* p = md + ((size_t)(h * SEQ) + qb + sub * 4 + i) * SEQ + kt * 64;
        #pragma unroll
        for (int j = 0; j < 16; ++j) {
          u32x4 t = ((const u32x4*)p)[j];
          ored |= t[0] | t[1] | t[2] | t[3];
          anded &= t[0] & t[1] & t[2] & t[3];
        }
      }
    }
    #pragma unroll
    for (int off = 8; off >= 1; off >>= 1) {
      ored |= __shfl_xor(ored, off);
      anded &= __shfl_xor(anded, off);
    }
    // all dwords equal && nonzero  ==> every element truthy (any dtype)
    if (sub == 0)
      tfl[kt] = (unsigned char)((ored != 0u ? 1 : 0) | ((ored == anded) ? 2 : 0));
  }
  __syncthreads();
  if (tid == 0) {
    int n = 0;
    for (int kt = 0; kt < 32; ++kt) {
      const unsigned f = tfl[kt];
      if (f & 1) lst[n++] = (unsigned char)(kt | ((f & 2) ? 0x80 : 0));
    }
    lcnt = n;
  }
  __syncthreads();
  const int cnt = lcnt;

  f32x4 oacc[4];
  #pragma unroll
  for (int nd = 0; nd < 4; ++nd) oacc[nd] = (f32x4){0.f, 0.f, 0.f, 0.f};
  float mrow[4], lrow[4];
  #pragma unroll
  for (int r = 0; r < 4; ++r) { mrow[r] = NEGINF; lrow[r] = 0.f; }

  const int n5 = rw * 64 + l;              // split-local thread 0..255
  const int vd = n5 >> 2, vc = n5 & 3;     // V gather coords (d-row, chunk)
  const size_t hb = (size_t)h * NT;

  auto computeTile = [&](unsigned e, const char* kbuf, const char* vbuf) {
    const int kb = (int)(e & 63) << 6;
    const int allT = (e & 0x80u) != 0;
    f32x4 sfr[2];
    sfr[0] = (f32x4){0.f, 0.f, 0.f, 0.f};
    sfr[1] = (f32x4){0.f, 0.f, 0.f, 0.f};
    #pragma unroll
    for (int nd2 = 0; nd2 < 2; ++nd2)
      #pragma unroll
      for (int ks = 0; ks < 2; ++ks) {
        bf16x8 bfr = *(const bf16x8*)(kbuf + swz(16 * nd2 + arow, ks * 64 + kgrp * 16));
        sfr[nd2] = __builtin_amdgcn_mfma_f32_16x16x32_bf16(qa[ks], bfr, sfr[nd2], 0, 0, 0);
      }
    #pragma unroll
    for (int r = 0; r < 4; ++r) {
      const int rloc = 16 * rw + kgrp * 4 + r;
      float sv[2];
      #pragma unroll
      for (int nd2 = 0; nd2 < 2; ++nd2) sv[nd2] = sfr[nd2][r] * SCALE;
      if (!allT) {
        const size_t rowoff = ((size_t)(h * SEQ) + qb + rloc) * SEQ + kb + 32 * s;
        #pragma unroll
        for (int nd2 = 0; nd2 < 2; ++nd2) {
          const size_t off = rowoff + 16 * nd2 + arow;
          const bool mv = byteMode ? (((const unsigned char*)maskg)[off] != 0)
                                   : (((const unsigned*)maskg)[off] != 0u);
          if (!mv) sv[nd2] = NEGINF;
        }
      }
      float tmax = fmaxf(sv[0], sv[1]);
      #pragma unroll
      for (int o2 = 8; o2 >= 1; o2 >>= 1) tmax = fmaxf(tmax, __shfl_xor(tmax, o2));
      const float mn = fmaxf(mrow[r], tmax);
      const float fac = __expf(mrow[r] - mn);
      float ps = 0.f;
      bf16 pb2[2];
      #pragma unroll
      for (int nd2 = 0; nd2 < 2; ++nd2) {
        const float p = (sv[nd2] > -1e20f) ? __expf(sv[nd2] - mn) : 0.f;
        ps += p; pb2[nd2] = (bf16)p;
      }
      #pragma unroll
      for (int o2 = 8; o2 >= 1; o2 >>= 1) ps += __shfl_xor(ps, o2);
      lrow[r] = lrow[r] * fac + ps;
      mrow[r] = mn;
      #pragma unroll
      for (int nd = 0; nd < 4; ++nd) oacc[nd][r] *= fac;
      #pragma unroll
      for (int nd2 = 0; nd2 < 2; ++nd2)
        *(bf16*)((char*)Pb[s] + swz(rloc, 2 * (16 * nd2 + arow))) = pb2[nd2];
    }
    bf16x8 ap = *(const bf16x8*)((char*)Pb[s] + swz(16 * rw + arow, kgrp * 16));
    #pragma unroll
    for (int nd = 0; nd < 4; ++nd) {
      bf16x8 bv = *(const bf16x8*)(vbuf + swz(16 * nd + arow, kgrp * 16));
      oacc[nd] = __builtin_amdgcn_mfma_f32_16x16x32_bf16(ap, bv, oacc[nd], 0, 0, 0);
    }
  };

  if constexpr (IMG) {
    if (cnt > 0) {
      const int kt0 = lst[0] & 63;
      const size_t toff = (hb + kt0) * IMG_TILE;
      gload_lds16(kimg + toff + 4096 * s + rw * 1024 + l * 16,
                  (char*)Kb[s][0] + rw * 1024 + l * 16);
      u32x4 vr = *(const u32x4*)(vimg + toff + vd * 128 + (((4 * s + vc) ^ (vd & 7)) << 4));
      *(u32x4*)((char*)Vb[s][0] + vd * 128 + ((vc ^ (vd & 7)) << 4)) = vr;
    }
    __syncthreads();
    for (int t = 0; t < cnt; ++t) {
      const int cur = t & 1;
      const unsigned e = lst[t];
      u32x4 vr;
      const bool hn = (t + 1 < cnt);
      if (hn) {
        const int ktn = lst[t + 1] & 63;
        const size_t toff = (hb + ktn) * IMG_TILE;
        gload_lds16(kimg + toff + 4096 * s + rw * 1024 + l * 16,
                    (char*)Kb[s][cur ^ 1] + rw * 1024 + l * 16);
        vr = *(const u32x4*)(vimg + toff + vd * 128 + (((4 * s + vc) ^ (vd & 7)) << 4));
      }
      computeTile(e, (const char*)Kb[s][cur], (const char*)Vb[s][cur]);
      if (hn)
        *(u32x4*)((char*)Vb[s][cur ^ 1] + vd * 128 + ((vc ^ (vd & 7)) << 4)) = vr;
      __syncthreads();
    }
  } else {
    const int row = n5 & 31, cq = n5 >> 5;   // f32 staging coords
    for (int t = 0; t < cnt; ++t) {
      const unsigned e = lst[t];
      const int kb32 = ((int)(e & 63) << 6) + 32 * s;
      {
        const float* kr = kg + ((size_t)(h * SEQ) + kb32 + row) * DH + cq * 8;
        f32x4 a0 = ((const f32x4*)kr)[0], a1 = ((const f32x4*)kr)[1];
        bf16x8 bb;
        #pragma unroll
        for (int j = 0; j < 4; ++j) { bb[j] = (bf16)a0[j]; bb[4 + j] = (bf16)a1[j]; }
        *(bf16x8*)((char*)Kb[s][0] + swz(row, cq * 16)) = bb;
        const float* vr2 = vg + ((size_t)(h * SEQ) + kb32 + row) * DH + cq * 8;
        f32x4 b0 = ((const f32x4*)vr2)[0], b1 = ((const f32x4*)vr2)[1];
        #pragma unroll
        for (int j = 0; j < 8; ++j) {
          const int d = cq * 8 + j;
          const float val = (j < 4) ? b0[j] : b1[j - 4];
          *(bf16*)((char*)Vb[s][0] + swz(d, 2 * row)) = (bf16)val;
        }
      }
      __syncthreads();
      computeTile(e, (const char*)Kb[s][0], (const char*)Vb[s][0]);
      __syncthreads();
    }
  }

  // ---- cross-split merge (split1 publishes, split0 combines+writes) ----
  __syncthreads();
  float* mg = (float*)&Vb[0][0][0];        // 25.6 KB <= 32 KB, V dead now
  const int mi = (rw * 64 + l) * 25;
  if (s == 1) {
    #pragma unroll
    for (int r = 0; r < 4; ++r) { mg[mi + r] = mrow[r]; mg[mi + 4 + r] = lrow[r]; }
    #pragma unroll
    for (int nd = 0; nd < 4; ++nd)
      #pragma unroll
      for (int r = 0; r < 4; ++r) mg[mi + 8 + nd * 4 + r] = oacc[nd][r];
  }
  __syncthreads();
  if (s == 0) {
    #pragma unroll
    for (int r = 0; r < 4; ++r) {
      const float m1 = mg[mi + r], l1 = mg[mi + 4 + r];
      const float ms = fmaxf(mrow[r], m1);
      const float f0 = __expf(mrow[r] - ms), f1 = __expf(m1 - ms);
      const float li = lrow[r] * f0 + l1 * f1;
      const float inv = (li > 0.f) ? (1.f / li) : 0.f;
      const int grow = qb + 16 * rw + kgrp * 4 + r;
      #pragma unroll
      for (int nd = 0; nd < 4; ++nd) {
        const float o = oacc[nd][r] * f0 + mg[mi + 8 + nd * 4 + r] * f1;
        outg[((size_t)(h * SEQ) + grow) * DH + 16 * nd + arow] = o * inv;
      }
    }
  }
}

extern "C" void kernel_launch(void* const* d_in, const int* in_sizes, int n_in,
                              void* d_out, int out_size, void* d_ws, size_t ws_size,
                              hipStream_t stream) {
  const float* q = (const float*)d_in[0];
  const float* k = (const float*)d_in[1];
  const float* v = (const float*)d_in[2];
  const void*  m = d_in[3];
  float* out = (float*)d_out;
  unsigned char* ws = (unsigned char*)d_ws;
  int* flag = (int*)ws;

  hipMemsetAsync(ws, 0, 64, stream);
  if (ws_size >= WS_NEED) {
    prep_kernel<true><<<512, 256, 0, stream>>>(k, v, m, ws + WS_KIMG, ws + WS_VIMG, flag);
    attn_kernel<true><<<512, 512, 0, stream>>>(q, k, v, m, out, flag,
                                               ws + WS_KIMG, ws + WS_VIMG);
  } else {
    prep_kernel<false><<<512, 256, 0, stream>>>(k, v, m, nullptr, nullptr, flag);
    attn_kernel<false><<<512, 512, 0, stream>>>(q, k, v, m, out, flag, nullptr, nullptr);
  }
}

// Round 4
// 88.589 us; speedup vs baseline: 1.7031x; 1.5023x over previous
//
#include <hip/hip_runtime.h>
#include <hip/hip_bf16.h>
#include <stdint.h>

typedef __bf16 bf16;
typedef __attribute__((ext_vector_type(8))) __bf16 bf16x8;
typedef __attribute__((ext_vector_type(4))) float f32x4;
typedef __attribute__((ext_vector_type(4))) unsigned int u32x4;

#define NH 16
#define SEQ 2048
#define DH 64
#define NT 32
#define SCALE 0.125f
#define NEGINF (-1e30f)
#define IMG_TILE 8192

// ws layout: [0,64) flag; [64, 64+512*64) tile lists; then K/V fragment images.
struct TileList { int count; int pad[3]; unsigned char e[32]; int pad2[4]; }; // 64 B
#define WS_LISTS 64
#define WS_KIMG  65536
#define WS_VIMG  (WS_KIMG + (size_t)NH * NT * IMG_TILE)
#define WS_NEED  (WS_VIMG + (size_t)NH * NT * IMG_TILE)

// XOR swizzle for the wave-private 16x64 bf16 P tile ([16][128B] rows).
__device__ __forceinline__ unsigned swz16(int row, int bytecol) {
  return (unsigned)(row * 128 + (bytecol ^ ((row & 7) << 4)));
}

// ---------------------------------------------------------------------------
// prep: (a) classify mask dtype from its first 4KB (identical data in every
// block -> grid-uniform result); (b) build per-(h,qtile) active-ktile lists
// with a fully coalesced scan; (c) [CONV] emit K and V^T in MFMA
// fragment-image layout (8 groups x 64 lanes x 16B per 64-row tile):
//   K  group g=(nd*2+ks), lane l: K[kb+16nd+(l&15)][ks*32+(l>>4)*8 + 0..7]
//   V  group g=(nd*2+ks), lane l: V[kb+ks*32+(l>>4)*8 + 0..7][16nd+(l&15)]
// Block b -> head h=b&15 (XCD-pinned), tile x=b>>4 (used as BOTH kt and qt).
// ---------------------------------------------------------------------------
template<bool CONV>
__global__ void __launch_bounds__(256) prep_kernel(
    const float* __restrict__ kg, const float* __restrict__ vg,
    const void* __restrict__ maskg, unsigned char* __restrict__ ws)
{
  const int b = blockIdx.x, tid = threadIdx.x;
  const int l = tid & 63, w = tid >> 6;
  const int h = b & 15, x = b >> 4;

  __shared__ int cls;
  __shared__ unsigned sOr[4][32], sAnd[4][32];
  __shared__ unsigned char tfl[32];

  if (tid == 0) cls = 0;
  __syncthreads();
  {  // dtype classify: byte-bool -> 0x01010101 dwords; int32-bool -> 1 dwords
    u32x4 t = ((const u32x4*)maskg)[tid];
    int bits = 0;
    #pragma unroll
    for (int j = 0; j < 4; ++j) {
      if (t[j] == 0x01010101u) bits |= 1;
      else if (t[j] == 1u) bits |= 2;
    }
    const int wb = (__any(bits & 1) ? 1 : 0) | (__any(bits & 2) ? 2 : 0);
    if (l == 0 && wb) atomicOr(&cls, wb);
  }
  __syncthreads();
  const int byteMode = ((cls & 1) || !(cls & 2)) ? 1 : 0;
  if (b == 0 && tid == 0) *(int*)ws = byteMode ? 1 : 2;

  // ---- K/V fragment-image conversion (tile x as ktile) ----
  if constexpr (CONV) {
    const int kb = x << 6;
    unsigned char* kimg = ws + WS_KIMG + (size_t)(h * NT + x) * IMG_TILE;
    unsigned char* vimg = ws + WS_VIMG + (size_t)(h * NT + x) * IMG_TILE;
    #pragma unroll
    for (int i = 0; i < 2; ++i) {
      const int g = 2 * w + i, nd = g >> 1, ks = g & 1;
      const float* kr = kg + ((size_t)(h * SEQ) + kb + 16 * nd + (l & 15)) * DH
                        + ks * 32 + (l >> 4) * 8;
      f32x4 a0 = ((const f32x4*)kr)[0], a1 = ((const f32x4*)kr)[1];
      bf16x8 kb8;
      #pragma unroll
      for (int j = 0; j < 4; ++j) { kb8[j] = (bf16)a0[j]; kb8[4 + j] = (bf16)a1[j]; }
      *(bf16x8*)(kimg + (g * 64 + l) * 16) = kb8;

      const float* vb = vg + ((size_t)(h * SEQ) + kb + ks * 32 + (l >> 4) * 8) * DH
                        + 16 * nd + (l & 15);
      bf16x8 vb8;
      #pragma unroll
      for (int j = 0; j < 8; ++j) vb8[j] = (bf16)vb[j * DH];
      *(bf16x8*)(vimg + (g * 64 + l) * 16) = vb8;
    }
  }

  // ---- coalesced mask scan (tile x as qtile) ----
  const int qb = x << 6;
  if (byteMode) {
    const unsigned char* st = (const unsigned char*)maskg + ((size_t)(h * SEQ) + qb) * SEQ;
    unsigned o0 = 0, a0 = 0xFFFFFFFFu, o1 = 0, a1 = 0xFFFFFFFFu;
    for (int p = 0; p < 16; ++p) {
      const int row = p * 4 + w;
      u32x4 ta = *(const u32x4*)(st + (size_t)row * SEQ + l * 16);
      u32x4 tb = *(const u32x4*)(st + (size_t)row * SEQ + 1024 + l * 16);
      o0 |= ta[0] | ta[1] | ta[2] | ta[3]; a0 &= ta[0] & ta[1] & ta[2] & ta[3];
      o1 |= tb[0] | tb[1] | tb[2] | tb[3]; a1 &= tb[0] & tb[1] & tb[2] & tb[3];
    }
    #pragma unroll
    for (int d = 1; d <= 2; d <<= 1) {   // 4 lanes span one 64B tile width
      o0 |= __shfl_xor(o0, d); a0 &= __shfl_xor(a0, d);
      o1 |= __shfl_xor(o1, d); a1 &= __shfl_xor(a1, d);
    }
    if ((l & 3) == 0) {
      sOr[w][l >> 2] = o0;        sAnd[w][l >> 2] = a0;
      sOr[w][16 + (l >> 2)] = o1; sAnd[w][16 + (l >> 2)] = a1;
    }
  } else {
    const unsigned char* st = (const unsigned char*)maskg + ((size_t)(h * SEQ) + qb) * SEQ * 4;
    unsigned oc[8], ac[8];
    #pragma unroll
    for (int c = 0; c < 8; ++c) { oc[c] = 0; ac[c] = 0xFFFFFFFFu; }
    for (int p = 0; p < 16; ++p) {
      const int row = p * 4 + w;
      #pragma unroll
      for (int c = 0; c < 8; ++c) {
        u32x4 t = *(const u32x4*)(st + (size_t)row * SEQ * 4 + c * 1024 + l * 16);
        oc[c] |= t[0] | t[1] | t[2] | t[3];
        ac[c] &= t[0] & t[1] & t[2] & t[3];
      }
    }
    #pragma unroll
    for (int d = 1; d <= 8; d <<= 1) {   // 16 lanes span one 256B tile width
      #pragma unroll
      for (int c = 0; c < 8; ++c) {
        oc[c] |= __shfl_xor(oc[c], d); ac[c] &= __shfl_xor(ac[c], d);
      }
    }
    if ((l & 15) == 0) {
      #pragma unroll
      for (int c = 0; c < 8; ++c) {
        sOr[w][c * 4 + (l >> 4)] = oc[c];
        sAnd[w][c * 4 + (l >> 4)] = ac[c];
      }
    }
  }
  __syncthreads();
  if (tid < 32) {
    const unsigned o = sOr[0][tid] | sOr[1][tid] | sOr[2][tid] | sOr[3][tid];
    const unsigned a = sAnd[0][tid] & sAnd[1][tid] & sAnd[2][tid] & sAnd[3][tid];
    int all = 0;
    if (o == a && a != 0u) {   // all granules identical & nonzero
      if (byteMode)            // additionally require every byte nonzero
        all = ((((a & 0x7F7F7F7Fu) + 0x7F7F7F7Fu) | a) & 0x80808080u) == 0x80808080u;
      else all = 1;
    }
    tfl[tid] = (unsigned char)((o != 0u ? 1 : 0) | (all ? 2 : 0));
  }
  __syncthreads();
  if (tid == 0) {
    TileList* L = (TileList*)(ws + WS_LISTS) + (h * NT + x);
    int n = 0;
    for (int kt = 0; kt < NT; ++kt) {
      const unsigned f = tfl[kt];
      if (f & 1) L->e[n++] = (unsigned char)(kt | ((f & 2) ? 0x80 : 0));
    }
    L->count = n;
  }
}

// ---------------------------------------------------------------------------
// attn: block = (h=bid&15, qt=bid>>4). 8 waves = rowwave rw(0..3) x tile-
// parity split s(0..1). Wave (rw,s): q-rows [qb+16rw, +16), tiles lst[i],
// i === s (mod 2), FULL 64 k-cols each. K/V fragments loaded directly from
// the global images (coalesced, L2-hot) -> NO barriers in the main loop.
// P transits wave-private LDS. One end-of-kernel merge across s.
// ---------------------------------------------------------------------------
template<bool IMG>
__global__ void __launch_bounds__(512, 4) attn_kernel(
    const float* __restrict__ qg, const float* __restrict__ kg,
    const float* __restrict__ vg, const void* __restrict__ maskg,
    float* __restrict__ outg, const unsigned char* __restrict__ ws)
{
  const int bid = blockIdx.x;
  const int h = bid & 15, qt = bid >> 4, qb = qt << 6;
  const int tid = threadIdx.x, l = tid & 63, w = tid >> 6;
  const int rw = w & 3, s = w >> 2;
  const int arow = l & 15, kgrp = l >> 4;
  const int byteMode = (*(const int*)ws == 2) ? 0 : 1;

  __shared__ __attribute__((aligned(16))) bf16 Pl[8][1024];   // 16x64 per wave
  __shared__ float mg[4][64][24];                             // merge buffer
  __shared__ unsigned char Ll[32];

  const TileList* L = (const TileList*)(ws + WS_LISTS) + (h * NT + qt);
  const int cnt = L->count;
  if (tid < 32) Ll[tid] = L->e[tid];

  // Q fragments: lane holds Q[qb+16rw+arow][ks*32+kgrp*8 .. +7]
  bf16x8 qa[2];
  {
    const float* qrow = qg + ((size_t)(h * SEQ) + qb + 16 * rw + arow) * DH;
    #pragma unroll
    for (int ks = 0; ks < 2; ++ks) {
      f32x4 x0 = *(const f32x4*)(qrow + ks * 32 + kgrp * 8);
      f32x4 x1 = *(const f32x4*)(qrow + ks * 32 + kgrp * 8 + 4);
      bf16x8 a;
      #pragma unroll
      for (int j = 0; j < 4; ++j) { a[j] = (bf16)x0[j]; a[4 + j] = (bf16)x1[j]; }
      qa[ks] = a;
    }
  }
  __syncthreads();   // Ll ready

  f32x4 oacc[4];
  #pragma unroll
  for (int nd = 0; nd < 4; ++nd) oacc[nd] = (f32x4){0.f, 0.f, 0.f, 0.f};
  float mrow[4], lrow[4];
  #pragma unroll
  for (int r = 0; r < 4; ++r) { mrow[r] = NEGINF; lrow[r] = 0.f; }

  const unsigned char* kimg = ws + WS_KIMG + (size_t)h * NT * IMG_TILE;
  const unsigned char* vimg = ws + WS_VIMG + (size_t)h * NT * IMG_TILE;

  for (int i = s; i < cnt; i += 2) {
    const unsigned e = Ll[i];
    const int kt = e & 63;
    const int allT = (e & 0x80u) != 0;
    const int kb = kt << 6;

    // ---- K fragments ----
    bf16x8 kf[8];
    if constexpr (IMG) {
      const unsigned char* kp = kimg + (size_t)kt * IMG_TILE + l * 16;
      #pragma unroll
      for (int g = 0; g < 8; ++g) kf[g] = *(const bf16x8*)(kp + g * 1024);
    } else {
      #pragma unroll
      for (int g = 0; g < 8; ++g) {
        const int nd = g >> 1, ks = g & 1;
        const float* kr = kg + ((size_t)(h * SEQ) + kb + 16 * nd + arow) * DH
                          + ks * 32 + kgrp * 8;
        f32x4 x0 = ((const f32x4*)kr)[0], x1 = ((const f32x4*)kr)[1];
        #pragma unroll
        for (int j = 0; j < 4; ++j) { kf[g][j] = (bf16)x0[j]; kf[g][4 + j] = (bf16)x1[j]; }
      }
    }

    // ---- S = Q K^T ----
    f32x4 sfr[4];
    #pragma unroll
    for (int nd = 0; nd < 4; ++nd) sfr[nd] = (f32x4){0.f, 0.f, 0.f, 0.f};
    #pragma unroll
    for (int nd = 0; nd < 4; ++nd)
      #pragma unroll
      for (int ks = 0; ks < 2; ++ks)
        sfr[nd] = __builtin_amdgcn_mfma_f32_16x16x32_bf16(qa[ks], kf[nd * 2 + ks], sfr[nd], 0, 0, 0);

    // ---- V fragments (latency hidden under softmax) ----
    bf16x8 vf[8];
    if constexpr (IMG) {
      const unsigned char* vp = vimg + (size_t)kt * IMG_TILE + l * 16;
      #pragma unroll
      for (int g = 0; g < 8; ++g) vf[g] = *(const bf16x8*)(vp + g * 1024);
    } else {
      #pragma unroll
      for (int g = 0; g < 8; ++g) {
        const int nd = g >> 1, ks = g & 1;
        const float* vb = vg + ((size_t)(h * SEQ) + kb + ks * 32 + kgrp * 8) * DH
                          + 16 * nd + arow;
        #pragma unroll
        for (int j = 0; j < 8; ++j) vf[g][j] = (bf16)vb[j * DH];
      }
    }

    // ---- online softmax; P -> wave-private LDS ----
    #pragma unroll
    for (int r = 0; r < 4; ++r) {
      const int rloc = kgrp * 4 + r;            // wave-local q row (0..15)
      float sv[4];
      #pragma unroll
      for (int nd = 0; nd < 4; ++nd) sv[nd] = sfr[nd][r] * SCALE;
      if (!allT) {
        const size_t rowoff = ((size_t)(h * SEQ) + qb + 16 * rw + rloc) * SEQ + kb;
        #pragma unroll
        for (int nd = 0; nd < 4; ++nd) {
          const size_t off = rowoff + 16 * nd + arow;
          const bool mv = byteMode ? (((const unsigned char*)maskg)[off] != 0)
                                   : (((const unsigned*)maskg)[off] != 0u);
          if (!mv) sv[nd] = NEGINF;
        }
      }
      float tmax = fmaxf(fmaxf(sv[0], sv[1]), fmaxf(sv[2], sv[3]));
      #pragma unroll
      for (int d = 8; d >= 1; d >>= 1) tmax = fmaxf(tmax, __shfl_xor(tmax, d));
      const float mn = fmaxf(mrow[r], tmax);
      const float fac = __expf(mrow[r] - mn);
      float ps = 0.f;
      bf16 pb[4];
      #pragma unroll
      for (int nd = 0; nd < 4; ++nd) {
        const float p = (sv[nd] > -1e20f) ? __expf(sv[nd] - mn) : 0.f;
        ps += p; pb[nd] = (bf16)p;
      }
      #pragma unroll
      for (int d = 8; d >= 1; d >>= 1) ps += __shfl_xor(ps, d);
      lrow[r] = lrow[r] * fac + ps;
      mrow[r] = mn;
      #pragma unroll
      for (int nd = 0; nd < 4; ++nd) {
        oacc[nd][r] *= fac;
        *(bf16*)((char*)Pl[w] + swz16(rloc, 2 * (16 * nd + arow))) = pb[nd];
      }
    }

    // ---- O += P V (same-wave P round-trip: lgkmcnt-ordered, no barrier) ----
    #pragma unroll
    for (int ks = 0; ks < 2; ++ks) {
      bf16x8 ap = *(const bf16x8*)((char*)Pl[w] + swz16(arow, ks * 64 + kgrp * 16));
      #pragma unroll
      for (int nd = 0; nd < 4; ++nd)
        oacc[nd] = __builtin_amdgcn_mfma_f32_16x16x32_bf16(ap, vf[nd * 2 + ks], oacc[nd], 0, 0, 0);
    }
  }

  // ---- merge the two parity splits; s==0 writes output ----
  if (s == 1) {
    float* mp = &mg[rw][l][0];
    #pragma unroll
    for (int r = 0; r < 4; ++r) { mp[r] = mrow[r]; mp[4 + r] = lrow[r]; }
    #pragma unroll
    for (int nd = 0; nd < 4; ++nd)
      #pragma unroll
      for (int r = 0; r < 4; ++r) mp[8 + nd * 4 + r] = oacc[nd][r];
  }
  __syncthreads();
  if (s == 0) {
    const float* mp = &mg[rw][l][0];
    #pragma unroll
    for (int r = 0; r < 4; ++r) {
      const float m1 = mp[r], l1 = mp[4 + r];
      const float ms = fmaxf(mrow[r], m1);
      const float f0 = __expf(mrow[r] - ms), f1 = __expf(m1 - ms);
      const float li = lrow[r] * f0 + l1 * f1;
      const float inv = (li > 0.f) ? (1.f / li) : 0.f;
      const int grow = qb + 16 * rw + kgrp * 4 + r;
      #pragma unroll
      for (int nd = 0; nd < 4; ++nd) {
        const float o = oacc[nd][r] * f0 + mp[8 + nd * 4 + r] * f1;
        outg[((size_t)(h * SEQ) + grow) * DH + 16 * nd + arow] = o * inv;
      }
    }
  }
}

extern "C" void kernel_launch(void* const* d_in, const int* in_sizes, int n_in,
                              void* d_out, int out_size, void* d_ws, size_t ws_size,
                              hipStream_t stream) {
  const float* q = (const float*)d_in[0];
  const float* k = (const float*)d_in[1];
  const float* v = (const float*)d_in[2];
  const void*  m = d_in[3];
  float* out = (float*)d_out;
  unsigned char* ws = (unsigned char*)d_ws;

  if (ws_size >= WS_NEED) {
    prep_kernel<true><<<NH * NT, 256, 0, stream>>>(k, v, m, ws);
    attn_kernel<true><<<NH * NT, 512, 0, stream>>>(q, k, v, m, out, ws);
  } else {
    prep_kernel<false><<<NH * NT, 256, 0, stream>>>(k, v, m, ws);
    attn_kernel<false><<<NH * NT, 512, 0, stream>>>(q, k, v, m, out, ws);
  }
}

// Round 5
// 81.343 us; speedup vs baseline: 1.8549x; 1.0891x over previous
//
#include <hip/hip_runtime.h>
#include <hip/hip_bf16.h>
#include <stdint.h>

typedef __bf16 bf16;
typedef __attribute__((ext_vector_type(4))) __bf16 bf16x4;
typedef __attribute__((ext_vector_type(8))) __bf16 bf16x8;
typedef __attribute__((ext_vector_type(4))) float f32x4;
typedef __attribute__((ext_vector_type(4))) unsigned int u32x4;

#define NH 16
#define SEQ 2048
#define DH 64
#define NT 32
#define SCALE 0.125f
#define NEGINF (-1e30f)
#define IMG_TILE 8192

// ws layout: [0,64) flag; [64, 64+512*64) tile lists; then K/V fragment images.
struct TileList { int count; int pad[3]; unsigned char e[32]; int pad2[4]; }; // 64 B
#define WS_LISTS 64
#define WS_KIMG  65536
#define WS_VIMG  (WS_KIMG + (size_t)NH * NT * IMG_TILE)
#define WS_NEED  (WS_VIMG + (size_t)NH * NT * IMG_TILE)

// XOR swizzle for the wave-private 16x64 bf16 P tile ([16][128B] rows).
__device__ __forceinline__ unsigned swz16(int row, int bytecol) {
  return (unsigned)(row * 128 + (bytecol ^ ((row & 7) << 4)));
}

// ---------------------------------------------------------------------------
// prep: (a) classify mask dtype from its first 4KB (identical data in every
// block -> grid-uniform result); (b) build per-(h,qtile) active-ktile lists
// with a fully coalesced scan; (c) [CONV] emit K and V^T in MFMA
// fragment-image layout (8 groups x 64 lanes x 16B per 64-row tile):
//   K  group g=(nd*2+ks), lane l: K[kb+16nd+(l&15)][ks*32+(l>>4)*8 + 0..7]
//   V  group g=(nd*2+ks), lane l: V[kb+ks*32+(l>>4)*8 + 0..7][16nd+(l&15)]
// Block b -> head h=b&15 (XCD-pinned), tile x=b>>4 (used as BOTH kt and qt).
// ---------------------------------------------------------------------------
template<bool CONV>
__global__ void __launch_bounds__(256) prep_kernel(
    const float* __restrict__ kg, const float* __restrict__ vg,
    const void* __restrict__ maskg, unsigned char* __restrict__ ws)
{
  const int b = blockIdx.x, tid = threadIdx.x;
  const int l = tid & 63, w = tid >> 6;
  const int h = b & 15, x = b >> 4;

  __shared__ int cls;
  __shared__ unsigned sOr[4][32], sAnd[4][32];
  __shared__ unsigned char tfl[32];

  if (tid == 0) cls = 0;
  __syncthreads();
  {  // dtype classify: byte-bool -> 0x01010101 dwords; int32-bool -> 1 dwords
    u32x4 t = ((const u32x4*)maskg)[tid];
    int bits = 0;
    #pragma unroll
    for (int j = 0; j < 4; ++j) {
      if (t[j] == 0x01010101u) bits |= 1;
      else if (t[j] == 1u) bits |= 2;
    }
    const int wb = (__any(bits & 1) ? 1 : 0) | (__any(bits & 2) ? 2 : 0);
    if (l == 0 && wb) atomicOr(&cls, wb);
  }
  __syncthreads();
  const int byteMode = ((cls & 1) || !(cls & 2)) ? 1 : 0;
  if (b == 0 && tid == 0) *(int*)ws = byteMode ? 1 : 2;

  // ---- K/V fragment-image conversion (tile x as ktile) ----
  if constexpr (CONV) {
    const int kb = x << 6;
    unsigned char* kimg = ws + WS_KIMG + (size_t)(h * NT + x) * IMG_TILE;
    unsigned char* vimg = ws + WS_VIMG + (size_t)(h * NT + x) * IMG_TILE;
    #pragma unroll
    for (int i = 0; i < 2; ++i) {
      const int g = 2 * w + i, nd = g >> 1, ks = g & 1;
      const float* kr = kg + ((size_t)(h * SEQ) + kb + 16 * nd + (l & 15)) * DH
                        + ks * 32 + (l >> 4) * 8;
      f32x4 a0 = ((const f32x4*)kr)[0], a1 = ((const f32x4*)kr)[1];
      bf16x8 kb8;
      #pragma unroll
      for (int j = 0; j < 4; ++j) { kb8[j] = (bf16)a0[j]; kb8[4 + j] = (bf16)a1[j]; }
      *(bf16x8*)(kimg + (g * 64 + l) * 16) = kb8;

      const float* vb = vg + ((size_t)(h * SEQ) + kb + ks * 32 + (l >> 4) * 8) * DH
                        + 16 * nd + (l & 15);
      bf16x8 vb8;
      #pragma unroll
      for (int j = 0; j < 8; ++j) vb8[j] = (bf16)vb[j * DH];
      *(bf16x8*)(vimg + (g * 64 + l) * 16) = vb8;
    }
  }

  // ---- coalesced mask scan (tile x as qtile) ----
  const int qb = x << 6;
  if (byteMode) {
    const unsigned char* st = (const unsigned char*)maskg + ((size_t)(h * SEQ) + qb) * SEQ;
    unsigned o0 = 0, a0 = 0xFFFFFFFFu, o1 = 0, a1 = 0xFFFFFFFFu;
    for (int p = 0; p < 16; ++p) {
      const int row = p * 4 + w;
      u32x4 ta = *(const u32x4*)(st + (size_t)row * SEQ + l * 16);
      u32x4 tb = *(const u32x4*)(st + (size_t)row * SEQ + 1024 + l * 16);
      o0 |= ta[0] | ta[1] | ta[2] | ta[3]; a0 &= ta[0] & ta[1] & ta[2] & ta[3];
      o1 |= tb[0] | tb[1] | tb[2] | tb[3]; a1 &= tb[0] & tb[1] & tb[2] & tb[3];
    }
    #pragma unroll
    for (int d = 1; d <= 2; d <<= 1) {   // 4 lanes span one 64B tile width
      o0 |= __shfl_xor(o0, d); a0 &= __shfl_xor(a0, d);
      o1 |= __shfl_xor(o1, d); a1 &= __shfl_xor(a1, d);
    }
    if ((l & 3) == 0) {
      sOr[w][l >> 2] = o0;        sAnd[w][l >> 2] = a0;
      sOr[w][16 + (l >> 2)] = o1; sAnd[w][16 + (l >> 2)] = a1;
    }
  } else {
    const unsigned char* st = (const unsigned char*)maskg + ((size_t)(h * SEQ) + qb) * SEQ * 4;
    unsigned oc[8], ac[8];
    #pragma unroll
    for (int c = 0; c < 8; ++c) { oc[c] = 0; ac[c] = 0xFFFFFFFFu; }
    for (int p = 0; p < 16; ++p) {
      const int row = p * 4 + w;
      #pragma unroll
      for (int c = 0; c < 8; ++c) {
        u32x4 t = *(const u32x4*)(st + (size_t)row * SEQ * 4 + c * 1024 + l * 16);
        oc[c] |= t[0] | t[1] | t[2] | t[3];
        ac[c] &= t[0] & t[1] & t[2] & t[3];
      }
    }
    #pragma unroll
    for (int d = 1; d <= 8; d <<= 1) {   // 16 lanes span one 256B tile width
      #pragma unroll
      for (int c = 0; c < 8; ++c) {
        oc[c] |= __shfl_xor(oc[c], d); ac[c] &= __shfl_xor(ac[c], d);
      }
    }
    if ((l & 15) == 0) {
      #pragma unroll
      for (int c = 0; c < 8; ++c) {
        sOr[w][c * 4 + (l >> 4)] = oc[c];
        sAnd[w][c * 4 + (l >> 4)] = ac[c];
      }
    }
  }
  __syncthreads();
  if (tid < 32) {
    const unsigned o = sOr[0][tid] | sOr[1][tid] | sOr[2][tid] | sOr[3][tid];
    const unsigned a = sAnd[0][tid] & sAnd[1][tid] & sAnd[2][tid] & sAnd[3][tid];
    int all = 0;
    if (o == a && a != 0u) {   // all granules identical & nonzero
      if (byteMode)            // additionally require every byte nonzero
        all = ((((a & 0x7F7F7F7Fu) + 0x7F7F7F7Fu) | a) & 0x80808080u) == 0x80808080u;
      else all = 1;
    }
    tfl[tid] = (unsigned char)((o != 0u ? 1 : 0) | (all ? 2 : 0));
  }
  __syncthreads();
  if (tid == 0) {
    TileList* L = (TileList*)(ws + WS_LISTS) + (h * NT + x);
    int n = 0;
    for (int kt = 0; kt < NT; ++kt) {
      const unsigned f = tfl[kt];
      if (f & 1) L->e[n++] = (unsigned char)(kt | ((f & 2) ? 0x80 : 0));
    }
    L->count = n;
  }
}

// ---------------------------------------------------------------------------
// attn: block = (h=bid&15, qt=bid>>4). 8 waves = rowwave rw(0..3) x tile-
// parity split s(0..1). SWAPPED-OPERAND layout (T12): S^T = mfma(K,Q) so
// lane qrow = l&15 owns one q-row; softmax = in-reg over 16 + 2 shuffles;
// O^T = mfma(V^T, P) keeps everything lane-local. P transits wave-private
// LDS (4x ds_write_b64 + 2x ds_read_b128). K frags for tile i+2 prefetched
// into freed registers during softmax. No barriers in the main loop.
// ---------------------------------------------------------------------------
template<bool IMG>
__global__ void __launch_bounds__(512, 4) attn_kernel(
    const float* __restrict__ qg, const float* __restrict__ kg,
    const float* __restrict__ vg, const void* __restrict__ maskg,
    float* __restrict__ outg, const unsigned char* __restrict__ ws)
{
  const int bid = blockIdx.x;
  const int h = bid & 15, qt = bid >> 4, qb = qt << 6;
  const int tid = threadIdx.x, l = tid & 63, w = tid >> 6;
  const int rw = w & 3, s = w >> 2;
  const int qrow = l & 15, kgrp = l >> 4;
  const int byteMode = (*(const int*)ws == 2) ? 0 : 1;

  __shared__ __attribute__((aligned(16))) bf16 Pl[8][1024];   // 16x64 per wave
  __shared__ float mg[4][64][19];                             // merge (pad 19)
  __shared__ unsigned char Ll[32];

  const TileList* L = (const TileList*)(ws + WS_LISTS) + (h * NT + qt);
  const int cnt = L->count;
  if (tid < 32) Ll[tid] = L->e[tid];

  // Q fragment (B-operand): lane holds Q[qb+16rw+qrow][ks*32+kgrp*8 + 0..7],
  // pre-scaled by 1/sqrt(D).
  bf16x8 qa[2];
  {
    const float* qp = qg + ((size_t)(h * SEQ) + qb + 16 * rw + qrow) * DH;
    #pragma unroll
    for (int ks = 0; ks < 2; ++ks) {
      f32x4 x0 = *(const f32x4*)(qp + ks * 32 + kgrp * 8);
      f32x4 x1 = *(const f32x4*)(qp + ks * 32 + kgrp * 8 + 4);
      bf16x8 a;
      #pragma unroll
      for (int j = 0; j < 4; ++j) {
        a[j] = (bf16)(x0[j] * SCALE); a[4 + j] = (bf16)(x1[j] * SCALE);
      }
      qa[ks] = a;
    }
  }
  __syncthreads();   // Ll ready

  f32x4 oacc[4];     // O^T frags: lane holds O[qrow][d = 16nd + 4kgrp + r]
  #pragma unroll
  for (int nd = 0; nd < 4; ++nd) oacc[nd] = (f32x4){0.f, 0.f, 0.f, 0.f};
  float mrun = NEGINF, lrun = 0.f;

  const unsigned char* kimg = ws + WS_KIMG + (size_t)h * NT * IMG_TILE;
  const unsigned char* vimg = ws + WS_VIMG + (size_t)h * NT * IMG_TILE;

  auto loadK = [&](bf16x8* kf, int kt) {
    if constexpr (IMG) {
      const unsigned char* kp = kimg + (size_t)kt * IMG_TILE + l * 16;
      #pragma unroll
      for (int g = 0; g < 8; ++g) kf[g] = *(const bf16x8*)(kp + g * 1024);
    } else {
      const int kb = kt << 6;
      #pragma unroll
      for (int g = 0; g < 8; ++g) {
        const int nd = g >> 1, ks = g & 1;
        const float* kr = kg + ((size_t)(h * SEQ) + kb + 16 * nd + qrow) * DH
                          + ks * 32 + kgrp * 8;
        f32x4 x0 = ((const f32x4*)kr)[0], x1 = ((const f32x4*)kr)[1];
        #pragma unroll
        for (int j = 0; j < 4; ++j) { kf[g][j] = (bf16)x0[j]; kf[g][4 + j] = (bf16)x1[j]; }
      }
    }
  };

  bf16x8 kf[8];
  if (s < cnt) loadK(kf, Ll[s] & 63);

  char* pw = (char*)Pl[w];

  for (int i = s; i < cnt; i += 2) {
    const unsigned e = Ll[i];
    const int kt = e & 63;
    const int allT = (e & 0x80u) != 0;
    const int kb = kt << 6;

    // ---- S^T = K Q^T : lane holds S[key = 16nd+4kgrp+r][qrow] ----
    f32x4 sfr[4];
    #pragma unroll
    for (int nd = 0; nd < 4; ++nd) sfr[nd] = (f32x4){0.f, 0.f, 0.f, 0.f};
    __builtin_amdgcn_s_setprio(1);
    #pragma unroll
    for (int nd = 0; nd < 4; ++nd)
      #pragma unroll
      for (int ks = 0; ks < 2; ++ks)
        sfr[nd] = __builtin_amdgcn_mfma_f32_16x16x32_bf16(kf[nd * 2 + ks], qa[ks], sfr[nd], 0, 0, 0);
    __builtin_amdgcn_s_setprio(0);

    // ---- prefetch next tile's K into freed kf regs (hidden by softmax) ----
    if (i + 2 < cnt) loadK(kf, Ll[i + 2] & 63);

    // ---- V^T fragments (A-operand; latency hidden by softmax) ----
    bf16x8 vf[8];
    if constexpr (IMG) {
      const unsigned char* vp = vimg + (size_t)kt * IMG_TILE + l * 16;
      #pragma unroll
      for (int g = 0; g < 8; ++g) vf[g] = *(const bf16x8*)(vp + g * 1024);
    } else {
      #pragma unroll
      for (int g = 0; g < 8; ++g) {
        const int nd = g >> 1, ks = g & 1;
        const float* vb = vg + ((size_t)(h * SEQ) + kb + ks * 32 + kgrp * 8) * DH
                          + 16 * nd + qrow;
        #pragma unroll
        for (int j = 0; j < 8; ++j) vf[g][j] = (bf16)vb[j * DH];
      }
    }

    // ---- mask (partial tiles only; never taken for tile-constant masks) ----
    if (!allT) {
      const size_t base = ((size_t)(h * SEQ) + qb + 16 * rw + qrow) * SEQ + kb + 4 * kgrp;
      #pragma unroll
      for (int nd = 0; nd < 4; ++nd)
        #pragma unroll
        for (int r = 0; r < 4; ++r) {
          const size_t off = base + 16 * nd + r;
          const bool mv = byteMode ? (((const unsigned char*)maskg)[off] != 0)
                                   : (((const unsigned*)maskg)[off] != 0u);
          if (!mv) sfr[nd][r] = NEGINF;
        }
    }

    // ---- per-lane online softmax (2 shuffles total) ----
    float mt;
    {
      f32x4 t0, t1;
      #pragma unroll
      for (int r = 0; r < 4; ++r) {
        t0[r] = fmaxf(sfr[0][r], sfr[1][r]);
        t1[r] = fmaxf(sfr[2][r], sfr[3][r]);
      }
      mt = fmaxf(fmaxf(fmaxf(t0[0], t0[1]), fmaxf(t0[2], t0[3])),
                 fmaxf(fmaxf(t1[0], t1[1]), fmaxf(t1[2], t1[3])));
    }
    mt = fmaxf(mt, __shfl_xor(mt, 16));
    mt = fmaxf(mt, __shfl_xor(mt, 32));
    const float mn = fmaxf(mrun, mt);
    const float fac = __expf(mrun - mn);
    float ls = 0.f;
    bf16x4 pb[4];
    #pragma unroll
    for (int nd = 0; nd < 4; ++nd)
      #pragma unroll
      for (int r = 0; r < 4; ++r) {
        const float p = (sfr[nd][r] > -1e20f) ? __expf(sfr[nd][r] - mn) : 0.f;
        ls += p; pb[nd][r] = (bf16)p;
      }
    ls += __shfl_xor(ls, 16);
    ls += __shfl_xor(ls, 32);
    lrun = lrun * fac + ls;
    mrun = mn;
    #pragma unroll
    for (int nd = 0; nd < 4; ++nd)
      #pragma unroll
      for (int r = 0; r < 4; ++r) oacc[nd][r] *= fac;

    // ---- P -> wave-private LDS (b64 writes), read back as B-frags ----
    #pragma unroll
    for (int nd = 0; nd < 4; ++nd)
      *(bf16x4*)(pw + swz16(qrow, 32 * nd + 8 * kgrp)) = pb[nd];
    bf16x8 ap[2];
    #pragma unroll
    for (int ks = 0; ks < 2; ++ks)
      ap[ks] = *(const bf16x8*)(pw + swz16(qrow, 64 * ks + 16 * kgrp));

    // ---- O^T += V^T P ----
    __builtin_amdgcn_s_setprio(1);
    #pragma unroll
    for (int ks = 0; ks < 2; ++ks)
      #pragma unroll
      for (int nd = 0; nd < 4; ++nd)
        oacc[nd] = __builtin_amdgcn_mfma_f32_16x16x32_bf16(vf[nd * 2 + ks], ap[ks], oacc[nd], 0, 0, 0);
    __builtin_amdgcn_s_setprio(0);
  }

  // ---- merge the two parity splits; s==0 writes output (lane-local) ----
  if (s == 1) {
    float* mp = &mg[rw][l][0];
    mp[0] = mrun; mp[1] = lrun;
    #pragma unroll
    for (int nd = 0; nd < 4; ++nd)
      #pragma unroll
      for (int r = 0; r < 4; ++r) mp[2 + nd * 4 + r] = oacc[nd][r];
  }
  __syncthreads();
  if (s == 0) {
    const float* mp = &mg[rw][l][0];
    const float m1 = mp[0], l1 = mp[1];
    const float ms = fmaxf(mrun, m1);
    const float f0 = __expf(mrun - ms), f1 = __expf(m1 - ms);
    const float li = lrun * f0 + l1 * f1;
    const float inv = (li > 0.f) ? (1.f / li) : 0.f;
    const int grow = qb + 16 * rw + qrow;
    float* op = outg + ((size_t)(h * SEQ) + grow) * DH + 4 * kgrp;
    #pragma unroll
    for (int nd = 0; nd < 4; ++nd) {
      f32x4 o;
      #pragma unroll
      for (int r = 0; r < 4; ++r)
        o[r] = (oacc[nd][r] * f0 + mp[2 + nd * 4 + r] * f1) * inv;
      *(f32x4*)(op + 16 * nd) = o;
    }
  }
}

extern "C" void kernel_launch(void* const* d_in, const int* in_sizes, int n_in,
                              void* d_out, int out_size, void* d_ws, size_t ws_size,
                              hipStream_t stream) {
  const float* q = (const float*)d_in[0];
  const float* k = (const float*)d_in[1];
  const float* v = (const float*)d_in[2];
  const void*  m = d_in[3];
  float* out = (float*)d_out;
  unsigned char* ws = (unsigned char*)d_ws;

  if (ws_size >= WS_NEED) {
    prep_kernel<true><<<NH * NT, 256, 0, stream>>>(k, v, m, ws);
    attn_kernel<true><<<NH * NT, 512, 0, stream>>>(q, k, v, m, out, ws);
  } else {
    prep_kernel<false><<<NH * NT, 256, 0, stream>>>(k, v, m, ws);
    attn_kernel<false><<<NH * NT, 512, 0, stream>>>(q, k, v, m, out, ws);
  }
}

// Round 6
// 78.286 us; speedup vs baseline: 1.9273x; 1.0390x over previous
//
#include <hip/hip_runtime.h>
#include <hip/hip_bf16.h>
#include <stdint.h>

typedef __bf16 bf16;
typedef __attribute__((ext_vector_type(4))) __bf16 bf16x4;
typedef __attribute__((ext_vector_type(8))) __bf16 bf16x8;
typedef __attribute__((ext_vector_type(4))) float f32x4;
typedef __attribute__((ext_vector_type(4))) unsigned int u32x4;

#define NH 16
#define SEQ 2048
#define DH 64
#define NT 32
#define SCALE 0.125f
#define NEGINF (-1e30f)
#define IMG_TILE 8192

// ws layout: [0,64) flag; [64, 64+512*64) tile lists; then K/V fragment images.
struct TileList { int count; int pad[3]; unsigned char e[32]; int pad2[4]; }; // 64 B
#define WS_LISTS 64
#define WS_KIMG  65536
#define WS_VIMG  (WS_KIMG + (size_t)NH * NT * IMG_TILE)
#define WS_NEED  (WS_VIMG + (size_t)NH * NT * IMG_TILE)

// XOR swizzle for the wave-private 16x64 bf16 P tile ([16][128B] rows).
__device__ __forceinline__ unsigned swz16(int row, int bytecol) {
  return (unsigned)(row * 128 + (bytecol ^ ((row & 7) << 4)));
}

// ---------------------------------------------------------------------------
// prep: (a) classify mask dtype from its first 4KB; (b) build per-(h,qtile)
// active-ktile lists with a coalesced scan; (c) [CONV] emit K and V^T in MFMA
// fragment-image layout (8 groups x 64 lanes x 16B per 64-row tile):
//   K  group g=(nd*2+ks), lane l: K[kb+16nd+(l&15)][ks*32+(l>>4)*8 + 0..7]
//   V  group g=(nd*2+ks), lane l: V[kb+ks*32+(l>>4)*8 + 0..7][16nd+(l&15)]
// Block b -> head h=b&15 (XCD-pinned), tile x=b>>4 (used as BOTH kt and qt).
// ---------------------------------------------------------------------------
template<bool CONV>
__global__ void __launch_bounds__(256) prep_kernel(
    const float* __restrict__ kg, const float* __restrict__ vg,
    const void* __restrict__ maskg, unsigned char* __restrict__ ws)
{
  const int b = blockIdx.x, tid = threadIdx.x;
  const int l = tid & 63, w = tid >> 6;
  const int h = b & 15, x = b >> 4;

  __shared__ int cls;
  __shared__ unsigned sOr[4][32], sAnd[4][32];
  __shared__ unsigned char tfl[32];

  if (tid == 0) cls = 0;
  __syncthreads();
  {  // dtype classify: byte-bool -> 0x01010101 dwords; int32-bool -> 1 dwords
    u32x4 t = ((const u32x4*)maskg)[tid];
    int bits = 0;
    #pragma unroll
    for (int j = 0; j < 4; ++j) {
      if (t[j] == 0x01010101u) bits |= 1;
      else if (t[j] == 1u) bits |= 2;
    }
    const int wb = (__any(bits & 1) ? 1 : 0) | (__any(bits & 2) ? 2 : 0);
    if (l == 0 && wb) atomicOr(&cls, wb);
  }
  __syncthreads();
  const int byteMode = ((cls & 1) || !(cls & 2)) ? 1 : 0;
  if (b == 0 && tid == 0) *(int*)ws = byteMode ? 1 : 2;

  // ---- K/V fragment-image conversion (tile x as ktile) ----
  if constexpr (CONV) {
    const int kb = x << 6;
    unsigned char* kimg = ws + WS_KIMG + (size_t)(h * NT + x) * IMG_TILE;
    unsigned char* vimg = ws + WS_VIMG + (size_t)(h * NT + x) * IMG_TILE;
    #pragma unroll
    for (int i = 0; i < 2; ++i) {
      const int g = 2 * w + i, nd = g >> 1, ks = g & 1;
      const float* kr = kg + ((size_t)(h * SEQ) + kb + 16 * nd + (l & 15)) * DH
                        + ks * 32 + (l >> 4) * 8;
      f32x4 a0 = ((const f32x4*)kr)[0], a1 = ((const f32x4*)kr)[1];
      bf16x8 kb8;
      #pragma unroll
      for (int j = 0; j < 4; ++j) { kb8[j] = (bf16)a0[j]; kb8[4 + j] = (bf16)a1[j]; }
      *(bf16x8*)(kimg + (g * 64 + l) * 16) = kb8;

      const float* vb = vg + ((size_t)(h * SEQ) + kb + ks * 32 + (l >> 4) * 8) * DH
                        + 16 * nd + (l & 15);
      bf16x8 vb8;
      #pragma unroll
      for (int j = 0; j < 8; ++j) vb8[j] = (bf16)vb[j * DH];
      *(bf16x8*)(vimg + (g * 64 + l) * 16) = vb8;
    }
  }

  // ---- coalesced mask scan (tile x as qtile) ----
  const int qb = x << 6;
  if (byteMode) {
    const unsigned char* st = (const unsigned char*)maskg + ((size_t)(h * SEQ) + qb) * SEQ;
    unsigned o0 = 0, a0 = 0xFFFFFFFFu, o1 = 0, a1 = 0xFFFFFFFFu;
    for (int p = 0; p < 16; ++p) {
      const int row = p * 4 + w;
      u32x4 ta = *(const u32x4*)(st + (size_t)row * SEQ + l * 16);
      u32x4 tb = *(const u32x4*)(st + (size_t)row * SEQ + 1024 + l * 16);
      o0 |= ta[0] | ta[1] | ta[2] | ta[3]; a0 &= ta[0] & ta[1] & ta[2] & ta[3];
      o1 |= tb[0] | tb[1] | tb[2] | tb[3]; a1 &= tb[0] & tb[1] & tb[2] & tb[3];
    }
    #pragma unroll
    for (int d = 1; d <= 2; d <<= 1) {   // 4 lanes span one 64B tile width
      o0 |= __shfl_xor(o0, d); a0 &= __shfl_xor(a0, d);
      o1 |= __shfl_xor(o1, d); a1 &= __shfl_xor(a1, d);
    }
    if ((l & 3) == 0) {
      sOr[w][l >> 2] = o0;        sAnd[w][l >> 2] = a0;
      sOr[w][16 + (l >> 2)] = o1; sAnd[w][16 + (l >> 2)] = a1;
    }
  } else {
    const unsigned char* st = (const unsigned char*)maskg + ((size_t)(h * SEQ) + qb) * SEQ * 4;
    unsigned oc[8], ac[8];
    #pragma unroll
    for (int c = 0; c < 8; ++c) { oc[c] = 0; ac[c] = 0xFFFFFFFFu; }
    for (int p = 0; p < 16; ++p) {
      const int row = p * 4 + w;
      #pragma unroll
      for (int c = 0; c < 8; ++c) {
        u32x4 t = *(const u32x4*)(st + (size_t)row * SEQ * 4 + c * 1024 + l * 16);
        oc[c] |= t[0] | t[1] | t[2] | t[3];
        ac[c] &= t[0] & t[1] & t[2] & t[3];
      }
    }
    #pragma unroll
    for (int d = 1; d <= 8; d <<= 1) {   // 16 lanes span one 256B tile width
      #pragma unroll
      for (int c = 0; c < 8; ++c) {
        oc[c] |= __shfl_xor(oc[c], d); ac[c] &= __shfl_xor(ac[c], d);
      }
    }
    if ((l & 15) == 0) {
      #pragma unroll
      for (int c = 0; c < 8; ++c) {
        sOr[w][c * 4 + (l >> 4)] = oc[c];
        sAnd[w][c * 4 + (l >> 4)] = ac[c];
      }
    }
  }
  __syncthreads();
  if (tid < 32) {
    const unsigned o = sOr[0][tid] | sOr[1][tid] | sOr[2][tid] | sOr[3][tid];
    const unsigned a = sAnd[0][tid] & sAnd[1][tid] & sAnd[2][tid] & sAnd[3][tid];
    int all = 0;
    if (o == a && a != 0u) {   // all granules identical & nonzero
      if (byteMode)            // additionally require every byte nonzero
        all = ((((a & 0x7F7F7F7Fu) + 0x7F7F7F7Fu) | a) & 0x80808080u) == 0x80808080u;
      else all = 1;
    }
    tfl[tid] = (unsigned char)((o != 0u ? 1 : 0) | (all ? 2 : 0));
  }
  __syncthreads();
  if (tid == 0) {
    TileList* L = (TileList*)(ws + WS_LISTS) + (h * NT + x);
    int n = 0;
    for (int kt = 0; kt < NT; ++kt) {
      const unsigned f = tfl[kt];
      if (f & 1) L->e[n++] = (unsigned char)(kt | ((f & 2) ? 0x80 : 0));
    }
    L->count = n;
  }
}

// ---------------------------------------------------------------------------
// attn: block = (h=bid&15, qt=bid>>4), 256 threads = 4 waves; wave rw owns
// q-rows [qb+16rw, +16) and walks the ENTIRE active-tile list (no split, no
// merge). SWAPPED-OPERAND layout: S^T = mfma(K,Q) so lane qrow = l&15 owns
// one q-row; softmax = in-reg over 16 + 2 shuffles; O^T = mfma(V^T, P).
// P transits wave-private LDS. K frags prefetched 1 tile ahead (issued right
// after QK frees them). launch_bounds(256,2): <=256 VGPR -> NO scratch
// spills (the R4/R5 (512,4)=128-VGPR cap forced in-loop spilling).
// ---------------------------------------------------------------------------
template<bool IMG>
__global__ void __launch_bounds__(256, 2) attn_kernel(
    const float* __restrict__ qg, const float* __restrict__ kg,
    const float* __restrict__ vg, const void* __restrict__ maskg,
    float* __restrict__ outg, const unsigned char* __restrict__ ws)
{
  const int bid = blockIdx.x;
  const int h = bid & 15, qt = bid >> 4, qb = qt << 6;
  const int tid = threadIdx.x, l = tid & 63, rw = tid >> 6;
  const int qrow = l & 15, kgrp = l >> 4;
  const int byteMode = (*(const int*)ws == 2) ? 0 : 1;

  __shared__ __attribute__((aligned(16))) bf16 Pl[4][1024];   // 16x64 per wave
  __shared__ unsigned char Ll[32];

  const TileList* L = (const TileList*)(ws + WS_LISTS) + (h * NT + qt);
  const int cnt = L->count;
  if (tid < 32) Ll[tid] = L->e[tid];

  // Q fragment (B-operand): lane holds Q[qb+16rw+qrow][ks*32+kgrp*8 + 0..7],
  // pre-scaled by 1/sqrt(D).
  bf16x8 qa[2];
  {
    const float* qp = qg + ((size_t)(h * SEQ) + qb + 16 * rw + qrow) * DH;
    #pragma unroll
    for (int ks = 0; ks < 2; ++ks) {
      f32x4 x0 = *(const f32x4*)(qp + ks * 32 + kgrp * 8);
      f32x4 x1 = *(const f32x4*)(qp + ks * 32 + kgrp * 8 + 4);
      bf16x8 a;
      #pragma unroll
      for (int j = 0; j < 4; ++j) {
        a[j] = (bf16)(x0[j] * SCALE); a[4 + j] = (bf16)(x1[j] * SCALE);
      }
      qa[ks] = a;
    }
  }
  __syncthreads();   // Ll ready

  f32x4 oacc[4];     // O^T frags: lane holds O[qrow][d = 16nd + 4kgrp + r]
  #pragma unroll
  for (int nd = 0; nd < 4; ++nd) oacc[nd] = (f32x4){0.f, 0.f, 0.f, 0.f};
  float mrun = NEGINF, lrun = 0.f;

  const unsigned char* kimg = ws + WS_KIMG + (size_t)h * NT * IMG_TILE;
  const unsigned char* vimg = ws + WS_VIMG + (size_t)h * NT * IMG_TILE;

  auto loadK = [&](bf16x8* kf, int kt) {
    if constexpr (IMG) {
      const unsigned char* kp = kimg + (size_t)kt * IMG_TILE + l * 16;
      #pragma unroll
      for (int g = 0; g < 8; ++g) kf[g] = *(const bf16x8*)(kp + g * 1024);
    } else {
      const int kb = kt << 6;
      #pragma unroll
      for (int g = 0; g < 8; ++g) {
        const int nd = g >> 1, ks = g & 1;
        const float* kr = kg + ((size_t)(h * SEQ) + kb + 16 * nd + qrow) * DH
                          + ks * 32 + kgrp * 8;
        f32x4 x0 = ((const f32x4*)kr)[0], x1 = ((const f32x4*)kr)[1];
        #pragma unroll
        for (int j = 0; j < 4; ++j) { kf[g][j] = (bf16)x0[j]; kf[g][4 + j] = (bf16)x1[j]; }
      }
    }
  };

  bf16x8 kf[8];
  if (cnt > 0) loadK(kf, Ll[0] & 63);

  char* pw = (char*)Pl[rw];

  for (int i = 0; i < cnt; ++i) {
    const unsigned e = Ll[i];
    const int kt = e & 63;
    const int allT = (e & 0x80u) != 0;
    const int kb = kt << 6;

    // ---- S^T = K Q^T : lane holds S[key = 16nd+4kgrp+r][qrow] ----
    f32x4 sfr[4];
    #pragma unroll
    for (int nd = 0; nd < 4; ++nd) sfr[nd] = (f32x4){0.f, 0.f, 0.f, 0.f};
    __builtin_amdgcn_s_setprio(1);
    #pragma unroll
    for (int nd = 0; nd < 4; ++nd)
      #pragma unroll
      for (int ks = 0; ks < 2; ++ks)
        sfr[nd] = __builtin_amdgcn_mfma_f32_16x16x32_bf16(kf[nd * 2 + ks], qa[ks], sfr[nd], 0, 0, 0);
    __builtin_amdgcn_s_setprio(0);

    // ---- prefetch next tile's K into freed kf regs (hidden by softmax) ----
    if (i + 1 < cnt) loadK(kf, Ll[i + 1] & 63);

    // ---- V^T fragments (A-operand; latency hidden by softmax) ----
    bf16x8 vf[8];
    if constexpr (IMG) {
      const unsigned char* vp = vimg + (size_t)kt * IMG_TILE + l * 16;
      #pragma unroll
      for (int g = 0; g < 8; ++g) vf[g] = *(const bf16x8*)(vp + g * 1024);
    } else {
      #pragma unroll
      for (int g = 0; g < 8; ++g) {
        const int nd = g >> 1, ks = g & 1;
        const float* vb = vg + ((size_t)(h * SEQ) + kb + ks * 32 + kgrp * 8) * DH
                          + 16 * nd + qrow;
        #pragma unroll
        for (int j = 0; j < 8; ++j) vf[g][j] = (bf16)vb[j * DH];
      }
    }

    // ---- mask (partial tiles only; never taken for tile-constant masks) ----
    if (!allT) {
      const size_t base = ((size_t)(h * SEQ) + qb + 16 * rw + qrow) * SEQ + kb + 4 * kgrp;
      #pragma unroll
      for (int nd = 0; nd < 4; ++nd)
        #pragma unroll
        for (int r = 0; r < 4; ++r) {
          const size_t off = base + 16 * nd + r;
          const bool mv = byteMode ? (((const unsigned char*)maskg)[off] != 0)
                                   : (((const unsigned*)maskg)[off] != 0u);
          if (!mv) sfr[nd][r] = NEGINF;
        }
    }

    // ---- per-lane online softmax (2 shuffles total) ----
    float mt;
    {
      f32x4 t0, t1;
      #pragma unroll
      for (int r = 0; r < 4; ++r) {
        t0[r] = fmaxf(sfr[0][r], sfr[1][r]);
        t1[r] = fmaxf(sfr[2][r], sfr[3][r]);
      }
      mt = fmaxf(fmaxf(fmaxf(t0[0], t0[1]), fmaxf(t0[2], t0[3])),
                 fmaxf(fmaxf(t1[0], t1[1]), fmaxf(t1[2], t1[3])));
    }
    mt = fmaxf(mt, __shfl_xor(mt, 16));
    mt = fmaxf(mt, __shfl_xor(mt, 32));
    const float mn = fmaxf(mrun, mt);
    const float fac = __expf(mrun - mn);
    float ls = 0.f;
    bf16x4 pb[4];
    #pragma unroll
    for (int nd = 0; nd < 4; ++nd)
      #pragma unroll
      for (int r = 0; r < 4; ++r) {
        const float p = (sfr[nd][r] > -1e20f) ? __expf(sfr[nd][r] - mn) : 0.f;
        ls += p; pb[nd][r] = (bf16)p;
      }
    ls += __shfl_xor(ls, 16);
    ls += __shfl_xor(ls, 32);
    lrun = lrun * fac + ls;
    mrun = mn;
    #pragma unroll
    for (int nd = 0; nd < 4; ++nd)
      #pragma unroll
      for (int r = 0; r < 4; ++r) oacc[nd][r] *= fac;

    // ---- P -> wave-private LDS (b64 writes), read back as B-frags ----
    #pragma unroll
    for (int nd = 0; nd < 4; ++nd)
      *(bf16x4*)(pw + swz16(qrow, 32 * nd + 8 * kgrp)) = pb[nd];
    bf16x8 ap[2];
    #pragma unroll
    for (int ks = 0; ks < 2; ++ks)
      ap[ks] = *(const bf16x8*)(pw + swz16(qrow, 64 * ks + 16 * kgrp));

    // ---- O^T += V^T P ----
    __builtin_amdgcn_s_setprio(1);
    #pragma unroll
    for (int ks = 0; ks < 2; ++ks)
      #pragma unroll
      for (int nd = 0; nd < 4; ++nd)
        oacc[nd] = __builtin_amdgcn_mfma_f32_16x16x32_bf16(vf[nd * 2 + ks], ap[ks], oacc[nd], 0, 0, 0);
    __builtin_amdgcn_s_setprio(0);
  }

  // ---- epilogue (lane-local, coalesced 16B stores) ----
  {
    const float inv = (lrun > 0.f) ? (1.f / lrun) : 0.f;
    const int grow = qb + 16 * rw + qrow;
    float* op = outg + ((size_t)(h * SEQ) + grow) * DH + 4 * kgrp;
    #pragma unroll
    for (int nd = 0; nd < 4; ++nd) {
      f32x4 o;
      #pragma unroll
      for (int r = 0; r < 4; ++r) o[r] = oacc[nd][r] * inv;
      *(f32x4*)(op + 16 * nd) = o;
    }
  }
}

extern "C" void kernel_launch(void* const* d_in, const int* in_sizes, int n_in,
                              void* d_out, int out_size, void* d_ws, size_t ws_size,
                              hipStream_t stream) {
  const float* q = (const float*)d_in[0];
  const float* k = (const float*)d_in[1];
  const float* v = (const float*)d_in[2];
  const void*  m = d_in[3];
  float* out = (float*)d_out;
  unsigned char* ws = (unsigned char*)d_ws;

  if (ws_size >= WS_NEED) {
    prep_kernel<true><<<NH * NT, 256, 0, stream>>>(k, v, m, ws);
    attn_kernel<true><<<NH * NT, 256, 0, stream>>>(q, k, v, m, out, ws);
  } else {
    prep_kernel<false><<<NH * NT, 256, 0, stream>>>(k, v, m, ws);
    attn_kernel<false><<<NH * NT, 256, 0, stream>>>(q, k, v, m, out, ws);
  }
}